// Round 20
// baseline (195.055 us; speedup 1.0000x reference)
//
#include <hip/hip_runtime.h>
#include <hip/hip_bf16.h>
#include <hip/hip_fp16.h>

namespace {

constexpr int N    = 65536;
constexpr int E    = 1048576;
constexpr int N2   = 2 * N;      // both sides concatenated
constexpr int B    = 128;
constexpr int NPG  = 512;
constexpr int IN   = 128;
constexpr int H    = 64;
constexpr int BINS = 16;
constexpr int FIN  = 2 * H + BINS + 3;  // 147
// CSR bucket scheme: 512 buckets of 256 dsts; 1024 slices of 2048 edges (2x parallelism).
constexpr int NBUCKET = 512;
constexpr int NSLICE  = 1024;
constexpr int SLICE_E = 2048;

typedef _Float16 f16x8 __attribute__((ext_vector_type(8)));
typedef float f32x16 __attribute__((ext_vector_type(16)));

union FragU { f16x8 v; unsigned int u[4]; };

__device__ __forceinline__ unsigned packh(float a, float b) {
  typedef __fp16 fp16x2 __attribute__((ext_vector_type(2)));
  union { fp16x2 h; unsigned u; } t;
  t.h = __builtin_amdgcn_cvt_pkrtz(a, b);
  return t.u;
}

__device__ __forceinline__ f16x8 ldf16x8(const __half* p) {
  return *(const f16x8*)(const void*)p;
}

// xw MFMA role: one 32-node tile per wave; y = x @ W1 -> fp16.
// MFMA conventions (HW-verified): A: lane holds A[row=lane&31][k=(lane>>5)*8+j];
// B: lane holds B[k=(lane>>5)*8+j][h=lane&31]; C/D: col=lane&31, row=(reg&3)+8*(reg>>2)+4*(lane>>5).
__device__ __forceinline__ void xw_tile(int nodebase, int lane, const float* __restrict__ x1,
                                        const float* __restrict__ x2, const float* __restrict__ W,
                                        __half* __restrict__ y) {
  const float* xp = (nodebase < N) ? (x1 + (size_t)nodebase * IN)
                                   : (x2 + (size_t)(nodebase - N) * IN);
  int r = lane & 31;
  int kh = lane >> 5;  // K-half select (0/1)
  const float* xrow = xp + (size_t)r * IN + kh * 8;
  f32x16 acc0, acc1;
#pragma unroll
  for (int i = 0; i < 16; ++i) { acc0[i] = 0.f; acc1[i] = 0.f; }
#pragma unroll
  for (int kk = 0; kk < 8; ++kk) {
    float4 a0 = *(const float4*)(xrow + kk * 16);
    float4 a1 = *(const float4*)(xrow + kk * 16 + 4);
    f16x8 af;
    af[0] = (_Float16)a0.x; af[1] = (_Float16)a0.y; af[2] = (_Float16)a0.z; af[3] = (_Float16)a0.w;
    af[4] = (_Float16)a1.x; af[5] = (_Float16)a1.y; af[6] = (_Float16)a1.z; af[7] = (_Float16)a1.w;
    const float* wbase = W + (size_t)(kk * 16 + kh * 8) * H + r;
    f16x8 b0, b1;
#pragma unroll
    for (int j = 0; j < 8; ++j) {
      b0[j] = (_Float16)wbase[j * H];
      b1[j] = (_Float16)wbase[j * H + 32];
    }
    acc0 = __builtin_amdgcn_mfma_f32_32x32x16_f16(af, b0, acc0, 0, 0, 0);
    acc1 = __builtin_amdgcn_mfma_f32_32x32x16_f16(af, b1, acc1, 0, 0, 0);
  }
#pragma unroll
  for (int reg = 0; reg < 16; ++reg) {
    int row = (reg & 3) + 8 * (reg >> 2) + 4 * kh;
    y[(size_t)(nodebase + row) * H + r]      = __float2half(acc0[reg]);
    y[(size_t)(nodebase + row) * H + r + 32] = __float2half(acc1[reg]);
  }
}

// ---------------- k_hist: bucket histogram (blocks 0..1023) + weight-transpose prep (1024..1039)
__global__ __launch_bounds__(256) void k_hist(const int* __restrict__ dst1, const int* __restrict__ dst2,
                                              int* __restrict__ bcnt,
                                              const float* __restrict__ Wa, const float* __restrict__ Wb,
                                              const float* __restrict__ Wc, __half* __restrict__ WaT,
                                              __half* __restrict__ WbT, __half* __restrict__ WcT) {
  __shared__ int hist[NBUCKET];                    // 2 KB
  int b = blockIdx.x, tid = threadIdx.x;
  if (b < NSLICE) {
    hist[tid] = 0;
    hist[tid + 256] = 0;
    __syncthreads();
    const int* d = (b < 512) ? dst1 : dst2;
    int ebase = (b & 511) * SLICE_E;
    int boff = (b < 512) ? 0 : 256;  // side2 dst+N -> bucket+256 (N = 256*256)
    for (int i = tid; i < SLICE_E; i += 256) atomicAdd(&hist[boff + (d[ebase + i] >> 8)], 1);
    __syncthreads();
    for (int k = tid; k < NBUCKET; k += 256) bcnt[b * NBUCKET + k] = hist[k];
  } else {
    int i = (b - NSLICE) * 256 + tid;  // 4096 total
    int k = i >> 6, h = i & 63;
    WaT[h * 64 + k] = __float2half(Wa[k * 64 + h]);
    WbT[h * 64 + k] = __float2half(Wb[k * 64 + h]);
    WcT[h * 64 + k] = __float2half(Wc[k * 64 + h]);
  }
}

// ---------------- k_scan_xw: per-bucket scan over 1024 slices (blocks 0..511) || xw side-1 ----
// Two-level scan: 4 slices/thread local prefix + 256-wide Hillis-Steele.
__global__ __launch_bounds__(256) void k_scan_xw(const int* __restrict__ bcnt, int* __restrict__ boffs,
                                                 int* __restrict__ tot,
                                                 const float* __restrict__ x1, const float* __restrict__ x2,
                                                 const float* __restrict__ W, __half* __restrict__ y) {
  __shared__ int s[256];
  int b = blockIdx.x, t = threadIdx.x;
  if (b < NBUCKET) {
    int base = t * 4;
    int v0 = bcnt[(size_t)(base + 0) * NBUCKET + b];
    int v1 = bcnt[(size_t)(base + 1) * NBUCKET + b];
    int v2 = bcnt[(size_t)(base + 2) * NBUCKET + b];
    int v3 = bcnt[(size_t)(base + 3) * NBUCKET + b];
    int q1 = v0, q2 = q1 + v1, q3 = q2 + v2, q4 = q3 + v3;  // local inclusive
    s[t] = q4;
    __syncthreads();
    for (int d = 1; d < 256; d <<= 1) {
      int a = (t >= d) ? s[t - d] : 0;
      __syncthreads();
      s[t] += a;
      __syncthreads();
    }
    int excl = s[t] - q4;
    boffs[(size_t)b * NSLICE + base + 0] = excl;
    boffs[(size_t)b * NSLICE + base + 1] = excl + q1;
    boffs[(size_t)b * NSLICE + base + 2] = excl + q2;
    boffs[(size_t)b * NSLICE + base + 3] = excl + q3;
    if (t == 255) tot[b] = s[255];
  } else {
    int wv = t >> 6, lane = t & 63;
    int nodebase = ((b - NBUCKET) * 4 + wv) * 32;  // nodes [0, N)
    xw_tile(nodebase, lane, x1, x2, W, y);
  }
}

// ---------------- k_p5_xw: P5 scatter (blocks 0..1023) || xw side-2 (1024..1535) ----------------
__global__ __launch_bounds__(256) void k_p5_xw(const int* __restrict__ src1, const int* __restrict__ dst1,
                                               const int* __restrict__ src2, const int* __restrict__ dst2,
                                               const int* __restrict__ boffs, const int* __restrict__ tot,
                                               int* __restrict__ ebuf,
                                               const float* __restrict__ x1, const float* __restrict__ x2,
                                               const float* __restrict__ W, __half* __restrict__ y) {
  __shared__ int stot[NBUCKET];
  __shared__ int sofs[NBUCKET];
  __shared__ int cur[NBUCKET];
  int b = blockIdx.x, tid = threadIdx.x;
  if (b < NSLICE) {
    int v0 = tot[tid], v1 = tot[tid + 256];
    stot[tid] = v0;
    stot[tid + 256] = v1;
    __syncthreads();
    for (int d = 1; d < NBUCKET; d <<= 1) {
      int a0 = (tid >= d) ? stot[tid - d] : 0;
      int a1 = (tid + 256 >= d) ? stot[tid + 256 - d] : 0;
      __syncthreads();
      stot[tid] += a0;
      stot[tid + 256] += a1;
      __syncthreads();
    }
    sofs[tid]       = stot[tid] - v0 + boffs[(size_t)tid * NSLICE + b];
    sofs[tid + 256] = stot[tid + 256] - v1 + boffs[(size_t)(tid + 256) * NSLICE + b];
    cur[tid] = 0;
    cur[tid + 256] = 0;
    __syncthreads();
    const int* sr = (b < 512) ? src1 : src2;
    const int* d  = (b < 512) ? dst1 : dst2;
    int ebase = (b & 511) * SLICE_E;
    int off = (b < 512) ? 0 : N;
    int boff2 = (b < 512) ? 0 : 256;
    for (int i = tid; i < SLICE_E; i += 256) {
      int dd = d[ebase + i];
      int sv = off + sr[ebase + i];
      int bucket = boff2 + (dd >> 8);
      int r = atomicAdd(&cur[bucket], 1);
      ebuf[sofs[bucket] + r] = ((dd & 255) << 17) | sv;
    }
  } else {
    int wv = tid >> 6, lane = tid & 63;
    int nodebase = N + ((b - NSLICE) * 4 + wv) * 32;  // nodes [N, 2N)
    xw_tile(nodebase, lane, x1, x2, W, y);
  }
}

// P6: per-bucket CSR finalize (contiguous edge segment). LDS count+scan+scatter.
__global__ __launch_bounds__(256) void k_p6(const int* __restrict__ ebuf, const int* __restrict__ tot,
                                            int* __restrict__ rowptr, int* __restrict__ col) {
  __shared__ int stot[NBUCKET];
  __shared__ int c256[256];
  __shared__ int lofs[256];
  int b = blockIdx.x, t = threadIdx.x;
  {
    int v0 = tot[t], v1 = tot[t + 256];
    stot[t] = v0;
    stot[t + 256] = v1;
    __syncthreads();
    for (int d = 1; d < NBUCKET; d <<= 1) {
      int a0 = (t >= d) ? stot[t - d] : 0;
      int a1 = (t + 256 >= d) ? stot[t + 256 - d] : 0;
      __syncthreads();
      stot[t] += a0;
      stot[t + 256] += a1;
      __syncthreads();
    }
  }
  int e0 = (b == 0) ? 0 : stot[b - 1];
  int e1 = stot[b];
  c256[t] = 0;
  __syncthreads();
  for (int i = e0 + t; i < e1; i += 256) atomicAdd(&c256[(ebuf[i] >> 17) & 255], 1);
  __syncthreads();
  int v = c256[t];
  lofs[t] = v;
  __syncthreads();
  for (int d = 1; d < 256; d <<= 1) {
    int a = (t >= d) ? lofs[t - d] : 0;
    __syncthreads();
    lofs[t] += a;
    __syncthreads();
  }
  int excl = lofs[t] - v;
  rowptr[b * 256 + t] = e0 + excl;
  if (b == 0 && t == 0) rowptr[N2] = 2 * E;
  c256[t] = 0;
  lofs[t] = excl;
  __syncthreads();
  for (int i = e0 + t; i < e1; i += 256) {
    int pk = ebuf[i];
    int dl = (pk >> 17) & 255;
    int r = atomicAdd(&c256[dl], 1);
    col[e0 + lofs[dl] + r] = pk & 0x1FFFF;
  }
}

// ---------------- gather: out[n] = relu(in[n] + sum_{j->n} in[j] + bias), fp16 rows ----------------
// TWO nodes per wave (32-lane groups, __half2 loads). ONE clamped 32-wide col load; lanes >= deg
// of c0 already hold col[last] -> constant shfl index, fully unconditional 16-deep load bursts.
// Pairwise fp16 pre-reduction (v_pk_add_f16); f32 master accumulators; duplicates removed by
// one subtract-correction.

__global__ __launch_bounds__(256) void k_gather(const __half* __restrict__ in, const int* __restrict__ rowptr,
                                                const int* __restrict__ col, const float* __restrict__ bias,
                                                __half* __restrict__ outb) {
  int tid = threadIdx.x;
  int lane32 = tid & 31;
  int n = blockIdx.x * 8 + (tid >> 5);
  const __half2* in2 = (const __half2*)in;     // row = 32 half2
  __half2* out2 = (__half2*)outb;
  float2 bias2 = ((const float2*)bias)[lane32];
  int p0 = rowptr[n], p1 = rowptr[n + 1];
  int deg = p1 - p0;
  int pc = (p1 - 1 > p0) ? p1 - 1 : p0;        // clamp target (deg==0 safe)
  int cidx = p0 + lane32;
  int c0 = col[cidx < pc ? cidx : pc];         // one coalesced 32-wide col load (tail-clamped)
  __half2 self = in2[(size_t)n * 32 + lane32];
  float ax = __half2float(self.x) + bias2.x;
  float ay = __half2float(self.y) + bias2.y;
  float cx = 0.f, cy = 0.f;
  if (deg > 0) {
    __half2 vl;
    {  // batch 0: edges 0..15, unconditional 16-deep burst; pairwise pk_add pre-reduce
      __half2 v[16];
#pragma unroll
      for (int i = 0; i < 16; ++i) {
        int c = __shfl(c0, i, 32);
        v[i] = in2[(size_t)c * 32 + lane32];
      }
#pragma unroll
      for (int i = 0; i < 16; i += 4) {
        __half2 w0 = __hadd2(v[i], v[i + 1]);
        __half2 w1 = __hadd2(v[i + 2], v[i + 3]);
        ax += __half2float(w0.x);
        ay += __half2float(w0.y);
        cx += __half2float(w1.x);
        cy += __half2float(w1.y);
      }
      vl = v[15];
    }
    if (deg > 16) {  // batch 1: edges 16..31
      __half2 v[16];
#pragma unroll
      for (int i = 0; i < 16; ++i) {
        int c = __shfl(c0, i + 16, 32);
        v[i] = in2[(size_t)c * 32 + lane32];
      }
#pragma unroll
      for (int i = 0; i < 16; i += 4) {
        __half2 w0 = __hadd2(v[i], v[i + 1]);
        __half2 w1 = __hadd2(v[i + 2], v[i + 3]);
        ax += __half2float(w0.x);
        ay += __half2float(w0.y);
        cx += __half2float(w1.x);
        cy += __half2float(w1.y);
      }
      vl = v[15];
    }
    if (deg > 32) {  // ultra-rare overflow (P ~ 2e-4 per node-half)
      for (int p = p0 + 32; p < p1; ++p) {
        int c = col[p];
        __half2 v = in2[(size_t)c * 32 + lane32];
        ax += __half2float(v.x);
        ay += __half2float(v.y);
      }
    }
    // correction: all duplicate slots hold the SAME row (col[pc]); vl holds it whenever dup>0
    int cov = (deg > 16) ? 32 : 16;
    int dup = cov - (deg < cov ? deg : cov);
    float fd = (float)dup;
    ax -= fd * __half2float(vl.x);
    ay -= fd * __half2float(vl.y);
  }
  __half2 o;
  o.x = __float2half(fmaxf(ax + cx, 0.f));
  o.y = __float2half(fmaxf(ay + cy, 0.f));
  out2[(size_t)n * 32 + lane32] = o;
}

// ---------------- k_mid via MFMA: z = relu(in@Wa + ba) @ Wb, all in registers ----------------
__global__ __launch_bounds__(256) void k_mid(const __half* __restrict__ in, const __half* __restrict__ WaT,
                                             const float* __restrict__ ba, const __half* __restrict__ WbT,
                                             __half* __restrict__ outb) {
  int tid = threadIdx.x, wv = tid >> 6, lane = tid & 63;
  int nodebase = (blockIdx.x * 4 + wv) * 32;
  int r = lane & 31, kh = lane >> 5;
  // ---- matmul 1 (swapped): acc0 = h1 rows 0..31, acc1 = h1 rows 32..63; cols = nodes
  f32x16 acc0, acc1;
#pragma unroll
  for (int i = 0; i < 16; ++i) { acc0[i] = 0.f; acc1[i] = 0.f; }
  const __half* brow = in + (size_t)(nodebase + r) * H + kh * 8;
#pragma unroll
  for (int kk = 0; kk < 4; ++kk) {
    f16x8 bf = ldf16x8(brow + kk * 16);
    f16x8 a0 = ldf16x8(WaT + (size_t)r * H + kk * 16 + kh * 8);
    f16x8 a1 = ldf16x8(WaT + (size_t)(r + 32) * H + kk * 16 + kh * 8);
    acc0 = __builtin_amdgcn_mfma_f32_32x32x16_f16(a0, bf, acc0, 0, 0, 0);
    acc1 = __builtin_amdgcn_mfma_f32_32x32x16_f16(a1, bf, acc1, 0, 0, 0);
  }
  // ---- bias + relu + pack to half pairs (rows = h1)
  float bav = ba[lane];  // lanes 0..63 cover h1 0..63
  unsigned p0[8], p1[8];
#pragma unroll
  for (int g2 = 0; g2 < 8; ++g2) {
    int regA = 2 * g2, regB = 2 * g2 + 1;
    int rowA = (regA & 3) + 8 * (regA >> 2) + 4 * kh;
    int rowB = (regB & 3) + 8 * (regB >> 2) + 4 * kh;
    float tA0 = fmaxf(acc0[regA] + __shfl(bav, rowA, 64), 0.f);
    float tB0 = fmaxf(acc0[regB] + __shfl(bav, rowB, 64), 0.f);
    float tA1 = fmaxf(acc1[regA] + __shfl(bav, rowA + 32, 64), 0.f);
    float tB1 = fmaxf(acc1[regB] + __shfl(bav, rowB + 32, 64), 0.f);
    p0[g2] = packh(tA0, tB0);
    p1[g2] = packh(tA1, tB1);
  }
  unsigned q0[8], q1[8];
#pragma unroll
  for (int i = 0; i < 8; ++i) {
    q0[i] = (unsigned)__shfl_xor((int)p0[i], 32, 64);
    q1[i] = (unsigned)__shfl_xor((int)p1[i], 32, 64);
  }
  // ---- matmul 2 (standard): out rows = nodes, cols = h2
  bool hi = (kh != 0);
  f32x16 o0, o1;
#pragma unroll
  for (int i = 0; i < 16; ++i) { o0[i] = 0.f; o1[i] = 0.f; }
#pragma unroll
  for (int kk = 0; kk < 4; ++kk) {
    const unsigned* P = (kk < 2) ? p0 : p1;
    const unsigned* Q = (kk < 2) ? q0 : q1;
    int s = kk & 1;
    FragU f;
    f.u[0] = hi ? Q[4 * s + 2] : P[4 * s + 0];
    f.u[1] = hi ? Q[4 * s + 3] : P[4 * s + 1];
    f.u[2] = hi ? P[4 * s + 2] : Q[4 * s + 0];
    f.u[3] = hi ? P[4 * s + 3] : Q[4 * s + 1];
    f16x8 b0 = ldf16x8(WbT + (size_t)r * H + kk * 16 + kh * 8);
    f16x8 b1 = ldf16x8(WbT + (size_t)(r + 32) * H + kk * 16 + kh * 8);
    o0 = __builtin_amdgcn_mfma_f32_32x32x16_f16(f.v, b0, o0, 0, 0, 0);
    o1 = __builtin_amdgcn_mfma_f32_32x32x16_f16(f.v, b1, o1, 0, 0, 0);
  }
#pragma unroll
  for (int reg = 0; reg < 16; ++reg) {
    int row = (reg & 3) + 8 * (reg >> 2) + 4 * kh;
    outb[(size_t)(nodebase + row) * H + r]      = __float2half(o0[reg]);
    outb[(size_t)(nodebase + row) * H + r + 32] = __float2half(o1[reg]);
  }
}

// ---------------- k_last via MFMA: h = relu(in@Wc + b4); normalize rows; pool partials ----
__global__ __launch_bounds__(256) void k_last(const __half* __restrict__ in, const __half* __restrict__ WcT,
                                              const float* __restrict__ b4, __half* __restrict__ outn,
                                              float* __restrict__ pg) {
  int tid = threadIdx.x, wv = tid >> 6, lane = tid & 63;
  int tile = blockIdx.x * 4 + wv;
  int nodebase = tile * 32;
  int r = lane & 31, kh = lane >> 5;
  f32x16 acc0, acc1;
#pragma unroll
  for (int i = 0; i < 16; ++i) { acc0[i] = 0.f; acc1[i] = 0.f; }
  const __half* arow = in + (size_t)(nodebase + r) * H + kh * 8;
#pragma unroll
  for (int kk = 0; kk < 4; ++kk) {
    f16x8 af = ldf16x8(arow + kk * 16);
    f16x8 b0 = ldf16x8(WcT + (size_t)r * H + kk * 16 + kh * 8);
    f16x8 b1 = ldf16x8(WcT + (size_t)(r + 32) * H + kk * 16 + kh * 8);
    acc0 = __builtin_amdgcn_mfma_f32_32x32x16_f16(af, b0, acc0, 0, 0, 0);
    acc1 = __builtin_amdgcn_mfma_f32_32x32x16_f16(af, b1, acc1, 0, 0, 0);
  }
  float bA = b4[r], bB = b4[r + 32];
  float psum0 = 0.f, psum1 = 0.f;
#pragma unroll
  for (int reg = 0; reg < 16; ++reg) {
    int row = (reg & 3) + 8 * (reg >> 2) + 4 * kh;
    float h0 = fmaxf(acc0[reg] + bA, 0.f);
    float h1 = fmaxf(acc1[reg] + bB, 0.f);
    psum0 += h0;
    psum1 += h1;
    float ss = h0 * h0 + h1 * h1;
#pragma unroll
    for (int d = 1; d < 32; d <<= 1) ss += __shfl_xor(ss, d, 64);
    float inv = 1.f / fmaxf(sqrtf(ss), 1e-12f);
    outn[(size_t)(nodebase + row) * H + r]      = __float2half(h0 * inv);
    outn[(size_t)(nodebase + row) * H + r + 32] = __float2half(h1 * inv);
  }
  psum0 += __shfl_xor(psum0, 32, 64);
  psum1 += __shfl_xor(psum1, 32, 64);
  if (kh == 0) {
    pg[tile * 64 + r]      = psum0;
    pg[tile * 64 + r + 32] = psum1;
  }
}

// ---------------- fused sim + hist + stats via MFMA (fp16 inputs, f32 accum) ----------------
__global__ __launch_bounds__(256) void k_sim(const __half* __restrict__ Hn, float* __restrict__ psum,
                                             float* __restrict__ psumsq, float* __restrict__ pmax,
                                             int* __restrict__ phist) {
  __shared__ int shist[64 * 17];   // 64 replicas, stride 17
  __shared__ float sfin[4][4];
  int tid = threadIdx.x, lane = tid & 63, wv = tid >> 6;
  int g = blockIdx.x >> 3, rt = blockIdx.x & 7;
  for (int i = tid; i < 64 * 17; i += 256) shist[i] = 0;
  __syncthreads();

  int rtile = wv & 1;   // 32-row subtile within the 64-row block tile
  int cgrp  = wv >> 1;  // col-tile group: 8 tiles of 32 cols each
  int arow = lane & 31;
  int koff = (lane >> 5) * 8;  // K-half select (identical formula for A and B)

  const __half* H1 = Hn + ((size_t)g * NPG + rt * 64 + rtile * 32 + arow) * H + koff;
  f16x8 afrag[4];
#pragma unroll
  for (int kk = 0; kk < 4; ++kk) afrag[kk] = ldf16x8(H1 + kk * 16);

  const __half* H2g = Hn + ((size_t)N + (size_t)g * NPG + arow) * H + koff;
  float lmax = -2.f, lsum = 0.f, lsumsq = 0.f;
  int rep = lane * 17;
#pragma unroll 1
  for (int t = 0; t < 8; ++t) {
    int ct = cgrp * 8 + t;
    const __half* B0 = H2g + (size_t)(ct * 32) * H;
    f32x16 acc;
#pragma unroll
    for (int r = 0; r < 16; ++r) acc[r] = 0.f;
#pragma unroll
    for (int kk = 0; kk < 4; ++kk) {
      f16x8 bfrag = ldf16x8(B0 + kk * 16);
      acc = __builtin_amdgcn_mfma_f32_32x32x16_f16(afrag[kk], bfrag, acc, 0, 0, 0);
    }
#pragma unroll
    for (int r = 0; r < 16; ++r) {
      float v = acc[r];
      lmax = fmaxf(lmax, v);
      lsum += v;
      lsumsq = fmaf(v, v, lsumsq);
      int bin = (int)((v + 1.f) * 8.f);  // trunc==floor for v>=-1; clamp handles rest
      bin = bin < 0 ? 0 : (bin > BINS - 1 ? BINS - 1 : bin);
      atomicAdd(&shist[rep + bin], 1);
    }
  }
#pragma unroll
  for (int d = 1; d < 64; d <<= 1) {
    lsum += __shfl_xor(lsum, d, 64);
    lsumsq += __shfl_xor(lsumsq, d, 64);
    lmax = fmaxf(lmax, __shfl_xor(lmax, d, 64));
  }
  if (lane == 0) {
    sfin[wv][0] = lsum;
    sfin[wv][1] = lsumsq;
    sfin[wv][2] = lmax;
  }
  __syncthreads();
  if (tid == 0) {
    psum[blockIdx.x] = sfin[0][0] + sfin[1][0] + sfin[2][0] + sfin[3][0];
    psumsq[blockIdx.x] = sfin[0][1] + sfin[1][1] + sfin[2][1] + sfin[3][1];
    pmax[blockIdx.x] = fmaxf(fmaxf(sfin[0][2], sfin[1][2]), fmaxf(sfin[2][2], sfin[3][2]));
  }
  if (tid < BINS) {
    int tot = 0;
    for (int r = 0; r < 64; ++r) tot += shist[r * 17 + tid];
    phist[blockIdx.x * BINS + tid] = tot;
  }
}

// ---------------- final feature assembly + MLP ----------------
__global__ __launch_bounds__(64) void k_final(const float* __restrict__ pg1, const float* __restrict__ pg2,
                                              const float* __restrict__ psum, const float* __restrict__ psumsq,
                                              const float* __restrict__ pmax, const int* __restrict__ phist,
                                              const float* __restrict__ w1, const float* __restrict__ b1,
                                              const float* __restrict__ w2, const float* __restrict__ b2,
                                              const float* __restrict__ w3, const float* __restrict__ b3,
                                              float* __restrict__ out) {
  __shared__ float f[FIN + 1];
  __shared__ float t1[64];
  __shared__ float t2[32];
  int g = blockIdx.x, t = threadIdx.x;
  {
    float s1v = 0.f, s2v = 0.f;
#pragma unroll
    for (int r = 0; r < 16; ++r) {
      s1v += pg1[(g * 16 + r) * 64 + t];
      s2v += pg2[(g * 16 + r) * 64 + t];
    }
    f[t]      = s1v * (1.f / NPG);
    f[64 + t] = s2v * (1.f / NPG);
  }
  if (t < BINS) {
    int tot = 0;
#pragma unroll
    for (int r = 0; r < 8; ++r) tot += phist[(g * 8 + r) * BINS + t];
    f[2 * H + t] = (float)tot * (1.f / 262144.f);
  }
  if (t == 0) {
    float s = 0.f, ss = 0.f, mx = -2.f;
#pragma unroll
    for (int r = 0; r < 8; ++r) {
      s += psum[g * 8 + r];
      ss += psumsq[g * 8 + r];
      mx = fmaxf(mx, pmax[g * 8 + r]);
    }
    const float inv = 1.f / 262144.f;
    float mean = s * inv;
    float var = fmaxf(ss * inv - mean * mean, 0.f);
    f[144] = mean;
    f[145] = mx;
    f[146] = sqrtf(var);
  }
  __syncthreads();
  float acc = b1[t];
  for (int k = 0; k < FIN; ++k) acc = fmaf(f[k], w1[k * 64 + t], acc);
  t1[t] = fmaxf(acc, 0.f);
  __syncthreads();
  if (t < 32) {
    float a2 = b2[t];
#pragma unroll 8
    for (int k = 0; k < 64; ++k) a2 = fmaf(t1[k], w2[k * 32 + t], a2);
    t2[t] = fmaxf(a2, 0.f);
  }
  __syncthreads();
  if (t == 0) {
    float a3 = b3[0];
#pragma unroll
    for (int k = 0; k < 32; ++k) a3 = fmaf(t2[k], w3[k], a3);
    out[g] = a3;
  }
}

}  // namespace

extern "C" void kernel_launch(void* const* d_in, const int* in_sizes, int n_in, void* d_out, int out_size,
                              void* d_ws, size_t ws_size, hipStream_t stream) {
  const float* x1 = (const float*)d_in[0];
  const int* e1 = (const int*)d_in[1];
  const float* x2 = (const float*)d_in[3];
  const int* e2 = (const int*)d_in[4];
  const float* enc_w1 = (const float*)d_in[6];
  const float* enc_b1 = (const float*)d_in[7];
  const float* enc_w2 = (const float*)d_in[8];
  const float* enc_b2 = (const float*)d_in[9];
  const float* enc_w3 = (const float*)d_in[10];
  const float* enc_b3 = (const float*)d_in[11];
  const float* enc_w4 = (const float*)d_in[12];
  const float* enc_b4 = (const float*)d_in[13];
  const float* mw1 = (const float*)d_in[14];
  const float* mb1 = (const float*)d_in[15];
  const float* mw2 = (const float*)d_in[16];
  const float* mb2 = (const float*)d_in[17];
  const float* mw3 = (const float*)d_in[18];
  const float* mb3 = (const float*)d_in[19];
  float* out = (float*)d_out;

  char* wsc = (char*)d_ws;
  size_t off = 0;
  auto alloc = [&](size_t bytes) -> void* {
    void* p = wsc + off;
    off += (bytes + 255) & ~(size_t)255;
    return p;
  };
  __half* Hn = (__half*)alloc((size_t)N2 * H * 2);        // 16 MB (normalized embeddings, fp16)
  __half* yH = (__half*)alloc((size_t)N2 * H * 2);        // 16 MB
  __half* tH = (__half*)alloc((size_t)N2 * H * 2);        // 16 MB (aliased as ebuf during CSR build)
  __half* zH = (__half*)alloc((size_t)N2 * H * 2);        // 16 MB
  __half* t2H = (__half*)alloc((size_t)N2 * H * 2);       // 16 MB
  int* rowptr = (int*)alloc((size_t)(N2 + 1) * 4);
  int* colidx = (int*)alloc((size_t)2 * E * 4);           // 8 MB
  int* bcnt = (int*)alloc((size_t)NSLICE * NBUCKET * 4);  // 2 MB
  int* boffs = (int*)alloc((size_t)NBUCKET * NSLICE * 4); // 2 MB
  int* tot = (int*)alloc((size_t)NBUCKET * 4);
  float* pg = (float*)alloc((size_t)(N2 / 32) * 64 * 4);  // 1 MB
  float* psum = (float*)alloc(1024 * 4);
  float* psumsq = (float*)alloc(1024 * 4);
  float* pmaxa = (float*)alloc(1024 * 4);
  int* phist = (int*)alloc((size_t)1024 * BINS * 4);
  __half* WaT = (__half*)alloc(4096 * 2);
  __half* WbT = (__half*)alloc(4096 * 2);
  __half* WcT = (__half*)alloc(4096 * 2);
  (void)ws_size;
  (void)in_sizes;
  (void)n_in;
  (void)out_size;

  const int* src1 = e1;
  const int* dst1 = e1 + E;
  const int* src2 = e2;
  const int* dst2 = e2 + E;
  int* ebuf = (int*)tH;  // 8 MB; consumed by k_p6 before k_gather writes tH

  // CSR build with xw MFMA overlapped; 1024 scatter slices for latency hiding
  k_hist<<<NSLICE + 16, 256, 0, stream>>>(dst1, dst2, bcnt, enc_w2, enc_w3, enc_w4, WaT, WbT, WcT);
  k_scan_xw<<<NBUCKET + 512, 256, 0, stream>>>(bcnt, boffs, tot, x1, x2, enc_w1, yH);
  k_p5_xw<<<NSLICE + 512, 256, 0, stream>>>(src1, dst1, src2, dst2, boffs, tot, ebuf, x1, x2, enc_w1, yH);
  k_p6<<<NBUCKET, 256, 0, stream>>>(ebuf, tot, rowptr, colidx);

  // encoder over 2N nodes (split kernels: gather = 2 nodes/wave, pk_add pre-reduce)
  k_gather<<<N2 / 8, 256, 0, stream>>>(yH, rowptr, colidx, enc_b1, tH);
  k_mid<<<N2 / 128, 256, 0, stream>>>(tH, WaT, enc_b2, WbT, zH);
  k_gather<<<N2 / 8, 256, 0, stream>>>(zH, rowptr, colidx, enc_b3, t2H);
  k_last<<<N2 / 128, 256, 0, stream>>>(t2H, WcT, enc_b4, Hn, pg);

  k_sim<<<B * 8, 256, 0, stream>>>(Hn, psum, psumsq, pmaxa, phist);
  k_final<<<B, 64, 0, stream>>>(pg, pg + (size_t)2048 * 64, psum, psumsq, pmaxa, phist, mw1, mb1, mw2, mb2,
                                mw3, mb3, out);
}

// Round 21
// 179.893 us; speedup vs baseline: 1.0843x; 1.0843x over previous
//
#include <hip/hip_runtime.h>
#include <hip/hip_bf16.h>
#include <hip/hip_fp16.h>

namespace {

constexpr int N    = 65536;
constexpr int E    = 1048576;
constexpr int N2   = 2 * N;      // both sides concatenated
constexpr int B    = 128;
constexpr int NPG  = 512;
constexpr int IN   = 128;
constexpr int H    = 64;
constexpr int BINS = 16;
constexpr int FIN  = 2 * H + BINS + 3;  // 147
// CSR bucket scheme: 512 buckets of 256 dsts; 512 slices of 4096 edges.
constexpr int NBUCKET = 512;
constexpr int NSLICE  = 512;
constexpr int SLICE_E = 4096;

typedef _Float16 f16x8 __attribute__((ext_vector_type(8)));
typedef float f32x16 __attribute__((ext_vector_type(16)));

union FragU { f16x8 v; unsigned int u[4]; };

__device__ __forceinline__ unsigned packh(float a, float b) {
  typedef __fp16 fp16x2 __attribute__((ext_vector_type(2)));
  union { fp16x2 h; unsigned u; } t;
  t.h = __builtin_amdgcn_cvt_pkrtz(a, b);
  return t.u;
}

__device__ __forceinline__ f16x8 ldf16x8(const __half* p) {
  return *(const f16x8*)(const void*)p;
}

// xw MFMA role: one 32-node tile per wave; y = x @ W1 -> fp16.
// MFMA conventions (HW-verified): A: lane holds A[row=lane&31][k=(lane>>5)*8+j];
// B: lane holds B[k=(lane>>5)*8+j][h=lane&31]; C/D: col=lane&31, row=(reg&3)+8*(reg>>2)+4*(lane>>5).
__device__ __forceinline__ void xw_tile(int nodebase, int lane, const float* __restrict__ x1,
                                        const float* __restrict__ x2, const float* __restrict__ W,
                                        __half* __restrict__ y) {
  const float* xp = (nodebase < N) ? (x1 + (size_t)nodebase * IN)
                                   : (x2 + (size_t)(nodebase - N) * IN);
  int r = lane & 31;
  int kh = lane >> 5;  // K-half select (0/1)
  const float* xrow = xp + (size_t)r * IN + kh * 8;
  f32x16 acc0, acc1;
#pragma unroll
  for (int i = 0; i < 16; ++i) { acc0[i] = 0.f; acc1[i] = 0.f; }
#pragma unroll
  for (int kk = 0; kk < 8; ++kk) {
    float4 a0 = *(const float4*)(xrow + kk * 16);
    float4 a1 = *(const float4*)(xrow + kk * 16 + 4);
    f16x8 af;
    af[0] = (_Float16)a0.x; af[1] = (_Float16)a0.y; af[2] = (_Float16)a0.z; af[3] = (_Float16)a0.w;
    af[4] = (_Float16)a1.x; af[5] = (_Float16)a1.y; af[6] = (_Float16)a1.z; af[7] = (_Float16)a1.w;
    const float* wbase = W + (size_t)(kk * 16 + kh * 8) * H + r;
    f16x8 b0, b1;
#pragma unroll
    for (int j = 0; j < 8; ++j) {
      b0[j] = (_Float16)wbase[j * H];
      b1[j] = (_Float16)wbase[j * H + 32];
    }
    acc0 = __builtin_amdgcn_mfma_f32_32x32x16_f16(af, b0, acc0, 0, 0, 0);
    acc1 = __builtin_amdgcn_mfma_f32_32x32x16_f16(af, b1, acc1, 0, 0, 0);
  }
#pragma unroll
  for (int reg = 0; reg < 16; ++reg) {
    int row = (reg & 3) + 8 * (reg >> 2) + 4 * kh;
    y[(size_t)(nodebase + row) * H + r]      = __float2half(acc0[reg]);
    y[(size_t)(nodebase + row) * H + r + 32] = __float2half(acc1[reg]);
  }
}

// ---------------- k_hist: bucket histogram (blocks 0..511) + weight-transpose prep (512..527)
__global__ __launch_bounds__(256) void k_hist(const int* __restrict__ dst1, const int* __restrict__ dst2,
                                              int* __restrict__ bcnt,
                                              const float* __restrict__ Wa, const float* __restrict__ Wb,
                                              const float* __restrict__ Wc, __half* __restrict__ WaT,
                                              __half* __restrict__ WbT, __half* __restrict__ WcT) {
  __shared__ int hist[NBUCKET];                    // 2 KB
  int b = blockIdx.x, tid = threadIdx.x;
  if (b < NSLICE) {
    hist[tid] = 0;
    hist[tid + 256] = 0;
    __syncthreads();
    const int* d = (b < 256) ? dst1 : dst2;
    int ebase = (b & 255) * SLICE_E;
    int boff = (b < 256) ? 0 : 256;  // side2 dst+N -> bucket+256 (N = 256*256)
    for (int i = tid; i < SLICE_E; i += 256) atomicAdd(&hist[boff + (d[ebase + i] >> 8)], 1);
    __syncthreads();
    for (int k = tid; k < NBUCKET; k += 256) bcnt[b * NBUCKET + k] = hist[k];
  } else {
    int i = (b - NSLICE) * 256 + tid;  // 4096 total
    int k = i >> 6, h = i & 63;
    WaT[h * 64 + k] = __float2half(Wa[k * 64 + h]);
    WbT[h * 64 + k] = __float2half(Wb[k * 64 + h]);
    WcT[h * 64 + k] = __float2half(Wc[k * 64 + h]);
  }
}

// ---------------- k_scan_xw: P2 scanrows (blocks 0..511) || xw side-1 (512..1023) ----------------
__global__ __launch_bounds__(256) void k_scan_xw(const int* __restrict__ bcnt, int* __restrict__ boffs,
                                                 int* __restrict__ tot,
                                                 const float* __restrict__ x1, const float* __restrict__ x2,
                                                 const float* __restrict__ W, __half* __restrict__ y) {
  __shared__ int s[NSLICE];
  int b = blockIdx.x, t = threadIdx.x;
  if (b < NBUCKET) {
    int v0 = bcnt[t * NBUCKET + b], v1 = bcnt[(t + 256) * NBUCKET + b];
    s[t] = v0;
    s[t + 256] = v1;
    __syncthreads();
    for (int d = 1; d < NSLICE; d <<= 1) {
      int a0 = (t >= d) ? s[t - d] : 0;
      int a1 = (t + 256 >= d) ? s[t + 256 - d] : 0;
      __syncthreads();
      s[t] += a0;
      s[t + 256] += a1;
      __syncthreads();
    }
    boffs[b * NSLICE + t] = s[t] - v0;
    boffs[b * NSLICE + t + 256] = s[t + 256] - v1;
    if (t == 255) tot[b] = s[NSLICE - 1];
  } else {
    int wv = t >> 6, lane = t & 63;
    int nodebase = ((b - NBUCKET) * 4 + wv) * 32;  // nodes [0, N)
    xw_tile(nodebase, lane, x1, x2, W, y);
  }
}

// ---------------- k_p5_xw: P5 scatter with LDS bucket-sort (blocks 0..511) || xw side-2 ------
// Slice-local bucket sort in LDS, then stream out in bucket order: 256 threads write
// ~monotonic global addresses (runs of avg 8 within each bucket) -> coalesced 64B lines
// instead of 2M random 4B stores. Global ebuf layout identical to the unsorted version.
__global__ __launch_bounds__(256) void k_p5_xw(const int* __restrict__ src1, const int* __restrict__ dst1,
                                               const int* __restrict__ src2, const int* __restrict__ dst2,
                                               const int* __restrict__ boffs, const int* __restrict__ tot,
                                               int* __restrict__ ebuf,
                                               const float* __restrict__ x1, const float* __restrict__ x2,
                                               const float* __restrict__ W, __half* __restrict__ y) {
  __shared__ int stot[NBUCKET];        // scan scratch (reused)
  __shared__ int sofs[NBUCKET];        // global position of this slice's run per bucket
  __shared__ int cnt[NBUCKET];
  __shared__ int lofs[NBUCKET];        // local (in-slice) exclusive bucket offsets
  __shared__ int sortedv[SLICE_E];     // 16 KB: values in bucket order
  __shared__ int sorteda[SLICE_E];     // 16 KB: global addresses in bucket order
  int b = blockIdx.x, tid = threadIdx.x;
  if (b < NSLICE) {
    // global bucket bases: scan tot
    int v0 = tot[tid], v1 = tot[tid + 256];
    stot[tid] = v0;
    stot[tid + 256] = v1;
    __syncthreads();
    for (int d = 1; d < NBUCKET; d <<= 1) {
      int a0 = (tid >= d) ? stot[tid - d] : 0;
      int a1 = (tid + 256 >= d) ? stot[tid + 256 - d] : 0;
      __syncthreads();
      stot[tid] += a0;
      stot[tid + 256] += a1;
      __syncthreads();
    }
    sofs[tid]       = stot[tid] - v0 + boffs[tid * NSLICE + b];
    sofs[tid + 256] = stot[tid + 256] - v1 + boffs[(tid + 256) * NSLICE + b];
    cnt[tid] = 0;
    cnt[tid + 256] = 0;
    __syncthreads();
    const int* sr = (b < 256) ? src1 : src2;
    const int* d  = (b < 256) ? dst1 : dst2;
    int ebase = (b & 255) * SLICE_E;
    int off = (b < 256) ? 0 : N;
    int boff2 = (b < 256) ? 0 : 256;
    int rb[16], vals[16];
#pragma unroll
    for (int i = 0; i < 16; ++i) {
      int e = ebase + tid + 256 * i;
      int dd = d[e];
      int sv = off + sr[e];
      int bucket = boff2 + (dd >> 8);
      int r = atomicAdd(&cnt[bucket], 1);
      rb[i] = (bucket << 12) | r;          // bucket 9b, rank <4096 12b
      vals[i] = ((dd & 255) << 17) | sv;
    }
    __syncthreads();
    // local exclusive scan of cnt (reuse stot as scratch)
    int c0 = cnt[tid], c1 = cnt[tid + 256];
    stot[tid] = c0;
    stot[tid + 256] = c1;
    __syncthreads();
    for (int d2 = 1; d2 < NBUCKET; d2 <<= 1) {
      int a0 = (tid >= d2) ? stot[tid - d2] : 0;
      int a1 = (tid + 256 >= d2) ? stot[tid + 256 - d2] : 0;
      __syncthreads();
      stot[tid] += a0;
      stot[tid + 256] += a1;
      __syncthreads();
    }
    lofs[tid] = stot[tid] - c0;
    lofs[tid + 256] = stot[tid + 256] - c1;
    __syncthreads();
    // place into bucket-sorted LDS arrays
#pragma unroll
    for (int i = 0; i < 16; ++i) {
      int bucket = rb[i] >> 12;
      int r = rb[i] & 4095;
      int lp = lofs[bucket] + r;
      sortedv[lp] = vals[i];
      sorteda[lp] = sofs[bucket] + r;
    }
    __syncthreads();
    // coalesced-ish stream-out
#pragma unroll
    for (int i = 0; i < 16; ++i) {
      int idx = tid + 256 * i;
      ebuf[sorteda[idx]] = sortedv[idx];
    }
  } else {
    int wv = tid >> 6, lane = tid & 63;
    int nodebase = N + ((b - NSLICE) * 4 + wv) * 32;  // nodes [N, 2N)
    xw_tile(nodebase, lane, x1, x2, W, y);
  }
}

// P6: per-bucket CSR finalize (contiguous edge segment). LDS count+scan+scatter.
__global__ __launch_bounds__(256) void k_p6(const int* __restrict__ ebuf, const int* __restrict__ tot,
                                            int* __restrict__ rowptr, int* __restrict__ col) {
  __shared__ int stot[NBUCKET];
  __shared__ int c256[256];
  __shared__ int lofs[256];
  int b = blockIdx.x, t = threadIdx.x;
  {
    int v0 = tot[t], v1 = tot[t + 256];
    stot[t] = v0;
    stot[t + 256] = v1;
    __syncthreads();
    for (int d = 1; d < NBUCKET; d <<= 1) {
      int a0 = (t >= d) ? stot[t - d] : 0;
      int a1 = (t + 256 >= d) ? stot[t + 256 - d] : 0;
      __syncthreads();
      stot[t] += a0;
      stot[t + 256] += a1;
      __syncthreads();
    }
  }
  int e0 = (b == 0) ? 0 : stot[b - 1];
  int e1 = stot[b];
  c256[t] = 0;
  __syncthreads();
  for (int i = e0 + t; i < e1; i += 256) atomicAdd(&c256[(ebuf[i] >> 17) & 255], 1);
  __syncthreads();
  int v = c256[t];
  lofs[t] = v;
  __syncthreads();
  for (int d = 1; d < 256; d <<= 1) {
    int a = (t >= d) ? lofs[t - d] : 0;
    __syncthreads();
    lofs[t] += a;
    __syncthreads();
  }
  int excl = lofs[t] - v;
  rowptr[b * 256 + t] = e0 + excl;
  if (b == 0 && t == 0) rowptr[N2] = 2 * E;
  c256[t] = 0;
  lofs[t] = excl;
  __syncthreads();
  for (int i = e0 + t; i < e1; i += 256) {
    int pk = ebuf[i];
    int dl = (pk >> 17) & 255;
    int r = atomicAdd(&c256[dl], 1);
    col[e0 + lofs[dl] + r] = pk & 0x1FFFF;
  }
}

// ---------------- gather: out[n] = relu(in[n] + sum_{j->n} in[j] + bias), fp16 rows ----------------
// TWO nodes per wave (32-lane groups, __half2 loads). ONE clamped 32-wide col load; lanes >= deg
// of c0 already hold col[last] -> constant shfl index, fully unconditional 16-deep load bursts.
// Pairwise fp16 pre-reduction (v_pk_add_f16); f32 master accumulators; duplicates removed by
// one subtract-correction.

__global__ __launch_bounds__(256) void k_gather(const __half* __restrict__ in, const int* __restrict__ rowptr,
                                                const int* __restrict__ col, const float* __restrict__ bias,
                                                __half* __restrict__ outb) {
  int tid = threadIdx.x;
  int lane32 = tid & 31;
  int n = blockIdx.x * 8 + (tid >> 5);
  const __half2* in2 = (const __half2*)in;     // row = 32 half2
  __half2* out2 = (__half2*)outb;
  float2 bias2 = ((const float2*)bias)[lane32];
  int p0 = rowptr[n], p1 = rowptr[n + 1];
  int deg = p1 - p0;
  int pc = (p1 - 1 > p0) ? p1 - 1 : p0;        // clamp target (deg==0 safe)
  int cidx = p0 + lane32;
  int c0 = col[cidx < pc ? cidx : pc];         // one coalesced 32-wide col load (tail-clamped)
  __half2 self = in2[(size_t)n * 32 + lane32];
  float ax = __half2float(self.x) + bias2.x;
  float ay = __half2float(self.y) + bias2.y;
  float cx = 0.f, cy = 0.f;
  if (deg > 0) {
    __half2 vl;
    {  // batch 0: edges 0..15, unconditional 16-deep burst; pairwise pk_add pre-reduce
      __half2 v[16];
#pragma unroll
      for (int i = 0; i < 16; ++i) {
        int c = __shfl(c0, i, 32);
        v[i] = in2[(size_t)c * 32 + lane32];
      }
#pragma unroll
      for (int i = 0; i < 16; i += 4) {
        __half2 w0 = __hadd2(v[i], v[i + 1]);
        __half2 w1 = __hadd2(v[i + 2], v[i + 3]);
        ax += __half2float(w0.x);
        ay += __half2float(w0.y);
        cx += __half2float(w1.x);
        cy += __half2float(w1.y);
      }
      vl = v[15];
    }
    if (deg > 16) {  // batch 1: edges 16..31
      __half2 v[16];
#pragma unroll
      for (int i = 0; i < 16; ++i) {
        int c = __shfl(c0, i + 16, 32);
        v[i] = in2[(size_t)c * 32 + lane32];
      }
#pragma unroll
      for (int i = 0; i < 16; i += 4) {
        __half2 w0 = __hadd2(v[i], v[i + 1]);
        __half2 w1 = __hadd2(v[i + 2], v[i + 3]);
        ax += __half2float(w0.x);
        ay += __half2float(w0.y);
        cx += __half2float(w1.x);
        cy += __half2float(w1.y);
      }
      vl = v[15];
    }
    if (deg > 32) {  // ultra-rare overflow (P ~ 2e-4 per node-half)
      for (int p = p0 + 32; p < p1; ++p) {
        int c = col[p];
        __half2 v = in2[(size_t)c * 32 + lane32];
        ax += __half2float(v.x);
        ay += __half2float(v.y);
      }
    }
    // correction: all duplicate slots hold the SAME row (col[pc]); vl holds it whenever dup>0
    int cov = (deg > 16) ? 32 : 16;
    int dup = cov - (deg < cov ? deg : cov);
    float fd = (float)dup;
    ax -= fd * __half2float(vl.x);
    ay -= fd * __half2float(vl.y);
  }
  __half2 o;
  o.x = __float2half(fmaxf(ax + cx, 0.f));
  o.y = __float2half(fmaxf(ay + cy, 0.f));
  out2[(size_t)n * 32 + lane32] = o;
}

// ---------------- k_mid via MFMA: z = relu(in@Wa + ba) @ Wb, all in registers ----------------
__global__ __launch_bounds__(256) void k_mid(const __half* __restrict__ in, const __half* __restrict__ WaT,
                                             const float* __restrict__ ba, const __half* __restrict__ WbT,
                                             __half* __restrict__ outb) {
  int tid = threadIdx.x, wv = tid >> 6, lane = tid & 63;
  int nodebase = (blockIdx.x * 4 + wv) * 32;
  int r = lane & 31, kh = lane >> 5;
  // ---- matmul 1 (swapped): acc0 = h1 rows 0..31, acc1 = h1 rows 32..63; cols = nodes
  f32x16 acc0, acc1;
#pragma unroll
  for (int i = 0; i < 16; ++i) { acc0[i] = 0.f; acc1[i] = 0.f; }
  const __half* brow = in + (size_t)(nodebase + r) * H + kh * 8;
#pragma unroll
  for (int kk = 0; kk < 4; ++kk) {
    f16x8 bf = ldf16x8(brow + kk * 16);
    f16x8 a0 = ldf16x8(WaT + (size_t)r * H + kk * 16 + kh * 8);
    f16x8 a1 = ldf16x8(WaT + (size_t)(r + 32) * H + kk * 16 + kh * 8);
    acc0 = __builtin_amdgcn_mfma_f32_32x32x16_f16(a0, bf, acc0, 0, 0, 0);
    acc1 = __builtin_amdgcn_mfma_f32_32x32x16_f16(a1, bf, acc1, 0, 0, 0);
  }
  // ---- bias + relu + pack to half pairs (rows = h1)
  float bav = ba[lane];  // lanes 0..63 cover h1 0..63
  unsigned p0[8], p1[8];
#pragma unroll
  for (int g2 = 0; g2 < 8; ++g2) {
    int regA = 2 * g2, regB = 2 * g2 + 1;
    int rowA = (regA & 3) + 8 * (regA >> 2) + 4 * kh;
    int rowB = (regB & 3) + 8 * (regB >> 2) + 4 * kh;
    float tA0 = fmaxf(acc0[regA] + __shfl(bav, rowA, 64), 0.f);
    float tB0 = fmaxf(acc0[regB] + __shfl(bav, rowB, 64), 0.f);
    float tA1 = fmaxf(acc1[regA] + __shfl(bav, rowA + 32, 64), 0.f);
    float tB1 = fmaxf(acc1[regB] + __shfl(bav, rowB + 32, 64), 0.f);
    p0[g2] = packh(tA0, tB0);
    p1[g2] = packh(tA1, tB1);
  }
  unsigned q0[8], q1[8];
#pragma unroll
  for (int i = 0; i < 8; ++i) {
    q0[i] = (unsigned)__shfl_xor((int)p0[i], 32, 64);
    q1[i] = (unsigned)__shfl_xor((int)p1[i], 32, 64);
  }
  // ---- matmul 2 (standard): out rows = nodes, cols = h2
  bool hi = (kh != 0);
  f32x16 o0, o1;
#pragma unroll
  for (int i = 0; i < 16; ++i) { o0[i] = 0.f; o1[i] = 0.f; }
#pragma unroll
  for (int kk = 0; kk < 4; ++kk) {
    const unsigned* P = (kk < 2) ? p0 : p1;
    const unsigned* Q = (kk < 2) ? q0 : q1;
    int s = kk & 1;
    FragU f;
    f.u[0] = hi ? Q[4 * s + 2] : P[4 * s + 0];
    f.u[1] = hi ? Q[4 * s + 3] : P[4 * s + 1];
    f.u[2] = hi ? P[4 * s + 2] : Q[4 * s + 0];
    f.u[3] = hi ? P[4 * s + 3] : Q[4 * s + 1];
    f16x8 b0 = ldf16x8(WbT + (size_t)r * H + kk * 16 + kh * 8);
    f16x8 b1 = ldf16x8(WbT + (size_t)(r + 32) * H + kk * 16 + kh * 8);
    o0 = __builtin_amdgcn_mfma_f32_32x32x16_f16(f.v, b0, o0, 0, 0, 0);
    o1 = __builtin_amdgcn_mfma_f32_32x32x16_f16(f.v, b1, o1, 0, 0, 0);
  }
#pragma unroll
  for (int reg = 0; reg < 16; ++reg) {
    int row = (reg & 3) + 8 * (reg >> 2) + 4 * kh;
    outb[(size_t)(nodebase + row) * H + r]      = __float2half(o0[reg]);
    outb[(size_t)(nodebase + row) * H + r + 32] = __float2half(o1[reg]);
  }
}

// ---------------- k_last via MFMA: h = relu(in@Wc + b4); normalize rows; pool partials ----
__global__ __launch_bounds__(256) void k_last(const __half* __restrict__ in, const __half* __restrict__ WcT,
                                              const float* __restrict__ b4, __half* __restrict__ outn,
                                              float* __restrict__ pg) {
  int tid = threadIdx.x, wv = tid >> 6, lane = tid & 63;
  int tile = blockIdx.x * 4 + wv;
  int nodebase = tile * 32;
  int r = lane & 31, kh = lane >> 5;
  f32x16 acc0, acc1;
#pragma unroll
  for (int i = 0; i < 16; ++i) { acc0[i] = 0.f; acc1[i] = 0.f; }
  const __half* arow = in + (size_t)(nodebase + r) * H + kh * 8;
#pragma unroll
  for (int kk = 0; kk < 4; ++kk) {
    f16x8 af = ldf16x8(arow + kk * 16);
    f16x8 b0 = ldf16x8(WcT + (size_t)r * H + kk * 16 + kh * 8);
    f16x8 b1 = ldf16x8(WcT + (size_t)(r + 32) * H + kk * 16 + kh * 8);
    acc0 = __builtin_amdgcn_mfma_f32_32x32x16_f16(af, b0, acc0, 0, 0, 0);
    acc1 = __builtin_amdgcn_mfma_f32_32x32x16_f16(af, b1, acc1, 0, 0, 0);
  }
  float bA = b4[r], bB = b4[r + 32];
  float psum0 = 0.f, psum1 = 0.f;
#pragma unroll
  for (int reg = 0; reg < 16; ++reg) {
    int row = (reg & 3) + 8 * (reg >> 2) + 4 * kh;
    float h0 = fmaxf(acc0[reg] + bA, 0.f);
    float h1 = fmaxf(acc1[reg] + bB, 0.f);
    psum0 += h0;
    psum1 += h1;
    float ss = h0 * h0 + h1 * h1;
#pragma unroll
    for (int d = 1; d < 32; d <<= 1) ss += __shfl_xor(ss, d, 64);
    float inv = 1.f / fmaxf(sqrtf(ss), 1e-12f);
    outn[(size_t)(nodebase + row) * H + r]      = __float2half(h0 * inv);
    outn[(size_t)(nodebase + row) * H + r + 32] = __float2half(h1 * inv);
  }
  psum0 += __shfl_xor(psum0, 32, 64);
  psum1 += __shfl_xor(psum1, 32, 64);
  if (kh == 0) {
    pg[tile * 64 + r]      = psum0;
    pg[tile * 64 + r + 32] = psum1;
  }
}

// ---------------- fused sim + hist + stats via MFMA (fp16 inputs, f32 accum) ----------------
__global__ __launch_bounds__(256) void k_sim(const __half* __restrict__ Hn, float* __restrict__ psum,
                                             float* __restrict__ psumsq, float* __restrict__ pmax,
                                             int* __restrict__ phist) {
  __shared__ int shist[64 * 17];   // 64 replicas, stride 17
  __shared__ float sfin[4][4];
  int tid = threadIdx.x, lane = tid & 63, wv = tid >> 6;
  int g = blockIdx.x >> 3, rt = blockIdx.x & 7;
  for (int i = tid; i < 64 * 17; i += 256) shist[i] = 0;
  __syncthreads();

  int rtile = wv & 1;   // 32-row subtile within the 64-row block tile
  int cgrp  = wv >> 1;  // col-tile group: 8 tiles of 32 cols each
  int arow = lane & 31;
  int koff = (lane >> 5) * 8;  // K-half select (identical formula for A and B)

  const __half* H1 = Hn + ((size_t)g * NPG + rt * 64 + rtile * 32 + arow) * H + koff;
  f16x8 afrag[4];
#pragma unroll
  for (int kk = 0; kk < 4; ++kk) afrag[kk] = ldf16x8(H1 + kk * 16);

  const __half* H2g = Hn + ((size_t)N + (size_t)g * NPG + arow) * H + koff;
  float lmax = -2.f, lsum = 0.f, lsumsq = 0.f;
  int rep = lane * 17;
#pragma unroll 1
  for (int t = 0; t < 8; ++t) {
    int ct = cgrp * 8 + t;
    const __half* B0 = H2g + (size_t)(ct * 32) * H;
    f32x16 acc;
#pragma unroll
    for (int r = 0; r < 16; ++r) acc[r] = 0.f;
#pragma unroll
    for (int kk = 0; kk < 4; ++kk) {
      f16x8 bfrag = ldf16x8(B0 + kk * 16);
      acc = __builtin_amdgcn_mfma_f32_32x32x16_f16(afrag[kk], bfrag, acc, 0, 0, 0);
    }
#pragma unroll
    for (int r = 0; r < 16; ++r) {
      float v = acc[r];
      lmax = fmaxf(lmax, v);
      lsum += v;
      lsumsq = fmaf(v, v, lsumsq);
      int bin = (int)((v + 1.f) * 8.f);  // trunc==floor for v>=-1; clamp handles rest
      bin = bin < 0 ? 0 : (bin > BINS - 1 ? BINS - 1 : bin);
      atomicAdd(&shist[rep + bin], 1);
    }
  }
#pragma unroll
  for (int d = 1; d < 64; d <<= 1) {
    lsum += __shfl_xor(lsum, d, 64);
    lsumsq += __shfl_xor(lsumsq, d, 64);
    lmax = fmaxf(lmax, __shfl_xor(lmax, d, 64));
  }
  if (lane == 0) {
    sfin[wv][0] = lsum;
    sfin[wv][1] = lsumsq;
    sfin[wv][2] = lmax;
  }
  __syncthreads();
  if (tid == 0) {
    psum[blockIdx.x] = sfin[0][0] + sfin[1][0] + sfin[2][0] + sfin[3][0];
    psumsq[blockIdx.x] = sfin[0][1] + sfin[1][1] + sfin[2][1] + sfin[3][1];
    pmax[blockIdx.x] = fmaxf(fmaxf(sfin[0][2], sfin[1][2]), fmaxf(sfin[2][2], sfin[3][2]));
  }
  if (tid < BINS) {
    int tot = 0;
    for (int r = 0; r < 64; ++r) tot += shist[r * 17 + tid];
    phist[blockIdx.x * BINS + tid] = tot;
  }
}

// ---------------- final feature assembly + MLP ----------------
__global__ __launch_bounds__(64) void k_final(const float* __restrict__ pg1, const float* __restrict__ pg2,
                                              const float* __restrict__ psum, const float* __restrict__ psumsq,
                                              const float* __restrict__ pmax, const int* __restrict__ phist,
                                              const float* __restrict__ w1, const float* __restrict__ b1,
                                              const float* __restrict__ w2, const float* __restrict__ b2,
                                              const float* __restrict__ w3, const float* __restrict__ b3,
                                              float* __restrict__ out) {
  __shared__ float f[FIN + 1];
  __shared__ float t1[64];
  __shared__ float t2[32];
  int g = blockIdx.x, t = threadIdx.x;
  {
    float s1v = 0.f, s2v = 0.f;
#pragma unroll
    for (int r = 0; r < 16; ++r) {
      s1v += pg1[(g * 16 + r) * 64 + t];
      s2v += pg2[(g * 16 + r) * 64 + t];
    }
    f[t]      = s1v * (1.f / NPG);
    f[64 + t] = s2v * (1.f / NPG);
  }
  if (t < BINS) {
    int tot = 0;
#pragma unroll
    for (int r = 0; r < 8; ++r) tot += phist[(g * 8 + r) * BINS + t];
    f[2 * H + t] = (float)tot * (1.f / 262144.f);
  }
  if (t == 0) {
    float s = 0.f, ss = 0.f, mx = -2.f;
#pragma unroll
    for (int r = 0; r < 8; ++r) {
      s += psum[g * 8 + r];
      ss += psumsq[g * 8 + r];
      mx = fmaxf(mx, pmax[g * 8 + r]);
    }
    const float inv = 1.f / 262144.f;
    float mean = s * inv;
    float var = fmaxf(ss * inv - mean * mean, 0.f);
    f[144] = mean;
    f[145] = mx;
    f[146] = sqrtf(var);
  }
  __syncthreads();
  float acc = b1[t];
  for (int k = 0; k < FIN; ++k) acc = fmaf(f[k], w1[k * 64 + t], acc);
  t1[t] = fmaxf(acc, 0.f);
  __syncthreads();
  if (t < 32) {
    float a2 = b2[t];
#pragma unroll 8
    for (int k = 0; k < 64; ++k) a2 = fmaf(t1[k], w2[k * 32 + t], a2);
    t2[t] = fmaxf(a2, 0.f);
  }
  __syncthreads();
  if (t == 0) {
    float a3 = b3[0];
#pragma unroll
    for (int k = 0; k < 32; ++k) a3 = fmaf(t2[k], w3[k], a3);
    out[g] = a3;
  }
}

}  // namespace

extern "C" void kernel_launch(void* const* d_in, const int* in_sizes, int n_in, void* d_out, int out_size,
                              void* d_ws, size_t ws_size, hipStream_t stream) {
  const float* x1 = (const float*)d_in[0];
  const int* e1 = (const int*)d_in[1];
  const float* x2 = (const float*)d_in[3];
  const int* e2 = (const int*)d_in[4];
  const float* enc_w1 = (const float*)d_in[6];
  const float* enc_b1 = (const float*)d_in[7];
  const float* enc_w2 = (const float*)d_in[8];
  const float* enc_b2 = (const float*)d_in[9];
  const float* enc_w3 = (const float*)d_in[10];
  const float* enc_b3 = (const float*)d_in[11];
  const float* enc_w4 = (const float*)d_in[12];
  const float* enc_b4 = (const float*)d_in[13];
  const float* mw1 = (const float*)d_in[14];
  const float* mb1 = (const float*)d_in[15];
  const float* mw2 = (const float*)d_in[16];
  const float* mb2 = (const float*)d_in[17];
  const float* mw3 = (const float*)d_in[18];
  const float* mb3 = (const float*)d_in[19];
  float* out = (float*)d_out;

  char* wsc = (char*)d_ws;
  size_t off = 0;
  auto alloc = [&](size_t bytes) -> void* {
    void* p = wsc + off;
    off += (bytes + 255) & ~(size_t)255;
    return p;
  };
  __half* Hn = (__half*)alloc((size_t)N2 * H * 2);        // 16 MB (normalized embeddings, fp16)
  __half* yH = (__half*)alloc((size_t)N2 * H * 2);        // 16 MB
  __half* tH = (__half*)alloc((size_t)N2 * H * 2);        // 16 MB (aliased as ebuf during CSR build)
  __half* zH = (__half*)alloc((size_t)N2 * H * 2);        // 16 MB
  __half* t2H = (__half*)alloc((size_t)N2 * H * 2);       // 16 MB
  int* rowptr = (int*)alloc((size_t)(N2 + 1) * 4);
  int* colidx = (int*)alloc((size_t)2 * E * 4);           // 8 MB
  int* bcnt = (int*)alloc((size_t)NSLICE * NBUCKET * 4);  // 1 MB
  int* boffs = (int*)alloc((size_t)NBUCKET * NSLICE * 4); // 1 MB
  int* tot = (int*)alloc((size_t)NBUCKET * 4);
  float* pg = (float*)alloc((size_t)(N2 / 32) * 64 * 4);  // 1 MB
  float* psum = (float*)alloc(1024 * 4);
  float* psumsq = (float*)alloc(1024 * 4);
  float* pmaxa = (float*)alloc(1024 * 4);
  int* phist = (int*)alloc((size_t)1024 * BINS * 4);
  __half* WaT = (__half*)alloc(4096 * 2);
  __half* WbT = (__half*)alloc(4096 * 2);
  __half* WcT = (__half*)alloc(4096 * 2);
  (void)ws_size;
  (void)in_sizes;
  (void)n_in;
  (void)out_size;

  const int* src1 = e1;
  const int* dst1 = e1 + E;
  const int* src2 = e2;
  const int* dst2 = e2 + E;
  int* ebuf = (int*)tH;  // 8 MB; consumed by k_p6 before k_gather writes tH

  // CSR build with xw MFMA overlapped; LDS bucket-sorted scatter for coalesced ebuf writes
  k_hist<<<NSLICE + 16, 256, 0, stream>>>(dst1, dst2, bcnt, enc_w2, enc_w3, enc_w4, WaT, WbT, WcT);
  k_scan_xw<<<NBUCKET + 512, 256, 0, stream>>>(bcnt, boffs, tot, x1, x2, enc_w1, yH);
  k_p5_xw<<<NSLICE + 512, 256, 0, stream>>>(src1, dst1, src2, dst2, boffs, tot, ebuf, x1, x2, enc_w1, yH);
  k_p6<<<NBUCKET, 256, 0, stream>>>(ebuf, tot, rowptr, colidx);

  // encoder over 2N nodes (split kernels: gather = 2 nodes/wave, pk_add pre-reduce)
  k_gather<<<N2 / 8, 256, 0, stream>>>(yH, rowptr, colidx, enc_b1, tH);
  k_mid<<<N2 / 128, 256, 0, stream>>>(tH, WaT, enc_b2, WbT, zH);
  k_gather<<<N2 / 8, 256, 0, stream>>>(zH, rowptr, colidx, enc_b3, t2H);
  k_last<<<N2 / 128, 256, 0, stream>>>(t2H, WcT, enc_b4, Hn, pg);

  k_sim<<<B * 8, 256, 0, stream>>>(Hn, psum, psumsq, pmaxa, phist);
  k_final<<<B, 64, 0, stream>>>(pg, pg + (size_t)2048 * 64, psum, psumsq, pmaxa, phist, mw1, mb1, mw2, mb2,
                                mw3, mb3, out);
}

// Round 22
// 178.892 us; speedup vs baseline: 1.0903x; 1.0056x over previous
//
#include <hip/hip_runtime.h>
#include <hip/hip_bf16.h>
#include <hip/hip_fp16.h>

namespace {

constexpr int N    = 65536;
constexpr int E    = 1048576;
constexpr int N2   = 2 * N;      // both sides concatenated
constexpr int B    = 128;
constexpr int NPG  = 512;
constexpr int IN   = 128;
constexpr int H    = 64;
constexpr int BINS = 16;
constexpr int FIN  = 2 * H + BINS + 3;  // 147
// CSR bucket scheme: 512 buckets of 256 dsts; 512 slices of 4096 edges.
constexpr int NBUCKET = 512;
constexpr int NSLICE  = 512;
constexpr int SLICE_E = 4096;

typedef _Float16 f16x8 __attribute__((ext_vector_type(8)));
typedef float f32x16 __attribute__((ext_vector_type(16)));

union FragU { f16x8 v; unsigned int u[4]; };

__device__ __forceinline__ unsigned packh(float a, float b) {
  typedef __fp16 fp16x2 __attribute__((ext_vector_type(2)));
  union { fp16x2 h; unsigned u; } t;
  t.h = __builtin_amdgcn_cvt_pkrtz(a, b);
  return t.u;
}

__device__ __forceinline__ f16x8 ldf16x8(const __half* p) {
  return *(const f16x8*)(const void*)p;
}

// xw MFMA role: one 32-node tile per wave; y = x @ W1 -> fp16.
// MFMA conventions (HW-verified): A: lane holds A[row=lane&31][k=(lane>>5)*8+j];
// B: lane holds B[k=(lane>>5)*8+j][h=lane&31]; C/D: col=lane&31, row=(reg&3)+8*(reg>>2)+4*(lane>>5).
__device__ __forceinline__ void xw_tile(int nodebase, int lane, const float* __restrict__ x1,
                                        const float* __restrict__ x2, const float* __restrict__ W,
                                        __half* __restrict__ y) {
  const float* xp = (nodebase < N) ? (x1 + (size_t)nodebase * IN)
                                   : (x2 + (size_t)(nodebase - N) * IN);
  int r = lane & 31;
  int kh = lane >> 5;  // K-half select (0/1)
  const float* xrow = xp + (size_t)r * IN + kh * 8;
  f32x16 acc0, acc1;
#pragma unroll
  for (int i = 0; i < 16; ++i) { acc0[i] = 0.f; acc1[i] = 0.f; }
#pragma unroll
  for (int kk = 0; kk < 8; ++kk) {
    float4 a0 = *(const float4*)(xrow + kk * 16);
    float4 a1 = *(const float4*)(xrow + kk * 16 + 4);
    f16x8 af;
    af[0] = (_Float16)a0.x; af[1] = (_Float16)a0.y; af[2] = (_Float16)a0.z; af[3] = (_Float16)a0.w;
    af[4] = (_Float16)a1.x; af[5] = (_Float16)a1.y; af[6] = (_Float16)a1.z; af[7] = (_Float16)a1.w;
    const float* wbase = W + (size_t)(kk * 16 + kh * 8) * H + r;
    f16x8 b0, b1;
#pragma unroll
    for (int j = 0; j < 8; ++j) {
      b0[j] = (_Float16)wbase[j * H];
      b1[j] = (_Float16)wbase[j * H + 32];
    }
    acc0 = __builtin_amdgcn_mfma_f32_32x32x16_f16(af, b0, acc0, 0, 0, 0);
    acc1 = __builtin_amdgcn_mfma_f32_32x32x16_f16(af, b1, acc1, 0, 0, 0);
  }
#pragma unroll
  for (int reg = 0; reg < 16; ++reg) {
    int row = (reg & 3) + 8 * (reg >> 2) + 4 * kh;
    y[(size_t)(nodebase + row) * H + r]      = __float2half(acc0[reg]);
    y[(size_t)(nodebase + row) * H + r + 32] = __float2half(acc1[reg]);
  }
}

// ---------------- k_hist: bucket histogram (blocks 0..511) + weight-transpose prep (512..527)
__global__ __launch_bounds__(256) void k_hist(const int* __restrict__ dst1, const int* __restrict__ dst2,
                                              int* __restrict__ bcnt,
                                              const float* __restrict__ Wa, const float* __restrict__ Wb,
                                              const float* __restrict__ Wc, __half* __restrict__ WaT,
                                              __half* __restrict__ WbT, __half* __restrict__ WcT) {
  __shared__ int hist[NBUCKET];                    // 2 KB
  int b = blockIdx.x, tid = threadIdx.x;
  if (b < NSLICE) {
    hist[tid] = 0;
    hist[tid + 256] = 0;
    __syncthreads();
    const int* d = (b < 256) ? dst1 : dst2;
    int ebase = (b & 255) * SLICE_E;
    int boff = (b < 256) ? 0 : 256;  // side2 dst+N -> bucket+256 (N = 256*256)
    for (int i = tid; i < SLICE_E; i += 256) atomicAdd(&hist[boff + (d[ebase + i] >> 8)], 1);
    __syncthreads();
    for (int k = tid; k < NBUCKET; k += 256) bcnt[b * NBUCKET + k] = hist[k];
  } else {
    int i = (b - NSLICE) * 256 + tid;  // 4096 total
    int k = i >> 6, h = i & 63;
    WaT[h * 64 + k] = __float2half(Wa[k * 64 + h]);
    WbT[h * 64 + k] = __float2half(Wb[k * 64 + h]);
    WcT[h * 64 + k] = __float2half(Wc[k * 64 + h]);
  }
}

// ---------------- k_scan_xw: P2 scanrows (blocks 0..511) || xw side-1 (512..1023) ----------------
__global__ __launch_bounds__(256) void k_scan_xw(const int* __restrict__ bcnt, int* __restrict__ boffs,
                                                 int* __restrict__ tot,
                                                 const float* __restrict__ x1, const float* __restrict__ x2,
                                                 const float* __restrict__ W, __half* __restrict__ y) {
  __shared__ int s[NSLICE];
  int b = blockIdx.x, t = threadIdx.x;
  if (b < NBUCKET) {
    int v0 = bcnt[t * NBUCKET + b], v1 = bcnt[(t + 256) * NBUCKET + b];
    s[t] = v0;
    s[t + 256] = v1;
    __syncthreads();
    for (int d = 1; d < NSLICE; d <<= 1) {
      int a0 = (t >= d) ? s[t - d] : 0;
      int a1 = (t + 256 >= d) ? s[t + 256 - d] : 0;
      __syncthreads();
      s[t] += a0;
      s[t + 256] += a1;
      __syncthreads();
    }
    boffs[b * NSLICE + t] = s[t] - v0;
    boffs[b * NSLICE + t + 256] = s[t + 256] - v1;
    if (t == 255) tot[b] = s[NSLICE - 1];
  } else {
    int wv = t >> 6, lane = t & 63;
    int nodebase = ((b - NBUCKET) * 4 + wv) * 32;  // nodes [0, N)
    xw_tile(nodebase, lane, x1, x2, W, y);
  }
}

// ---------------- k_p5_xw: P5 scatter with LDS bucket-sort (blocks 0..511) || xw side-2 ------
// Slice-local bucket sort in LDS, then stream out in bucket order: coalesced ebuf writes.
__global__ __launch_bounds__(256) void k_p5_xw(const int* __restrict__ src1, const int* __restrict__ dst1,
                                               const int* __restrict__ src2, const int* __restrict__ dst2,
                                               const int* __restrict__ boffs, const int* __restrict__ tot,
                                               int* __restrict__ ebuf,
                                               const float* __restrict__ x1, const float* __restrict__ x2,
                                               const float* __restrict__ W, __half* __restrict__ y) {
  __shared__ int stot[NBUCKET];        // scan scratch (reused)
  __shared__ int sofs[NBUCKET];        // global position of this slice's run per bucket
  __shared__ int cnt[NBUCKET];
  __shared__ int lofs[NBUCKET];        // local (in-slice) exclusive bucket offsets
  __shared__ int sortedv[SLICE_E];     // 16 KB: values in bucket order
  __shared__ int sorteda[SLICE_E];     // 16 KB: global addresses in bucket order
  int b = blockIdx.x, tid = threadIdx.x;
  if (b < NSLICE) {
    // global bucket bases: scan tot
    int v0 = tot[tid], v1 = tot[tid + 256];
    stot[tid] = v0;
    stot[tid + 256] = v1;
    __syncthreads();
    for (int d = 1; d < NBUCKET; d <<= 1) {
      int a0 = (tid >= d) ? stot[tid - d] : 0;
      int a1 = (tid + 256 >= d) ? stot[tid + 256 - d] : 0;
      __syncthreads();
      stot[tid] += a0;
      stot[tid + 256] += a1;
      __syncthreads();
    }
    sofs[tid]       = stot[tid] - v0 + boffs[tid * NSLICE + b];
    sofs[tid + 256] = stot[tid + 256] - v1 + boffs[(tid + 256) * NSLICE + b];
    cnt[tid] = 0;
    cnt[tid + 256] = 0;
    __syncthreads();
    const int* sr = (b < 256) ? src1 : src2;
    const int* d  = (b < 256) ? dst1 : dst2;
    int ebase = (b & 255) * SLICE_E;
    int off = (b < 256) ? 0 : N;
    int boff2 = (b < 256) ? 0 : 256;
    int rb[16], vals[16];
#pragma unroll
    for (int i = 0; i < 16; ++i) {
      int e = ebase + tid + 256 * i;
      int dd = d[e];
      int sv = off + sr[e];
      int bucket = boff2 + (dd >> 8);
      int r = atomicAdd(&cnt[bucket], 1);
      rb[i] = (bucket << 12) | r;          // bucket 9b, rank <4096 12b
      vals[i] = ((dd & 255) << 17) | sv;
    }
    __syncthreads();
    // local exclusive scan of cnt (reuse stot as scratch)
    int c0 = cnt[tid], c1 = cnt[tid + 256];
    stot[tid] = c0;
    stot[tid + 256] = c1;
    __syncthreads();
    for (int d2 = 1; d2 < NBUCKET; d2 <<= 1) {
      int a0 = (tid >= d2) ? stot[tid - d2] : 0;
      int a1 = (tid + 256 >= d2) ? stot[tid + 256 - d2] : 0;
      __syncthreads();
      stot[tid] += a0;
      stot[tid + 256] += a1;
      __syncthreads();
    }
    lofs[tid] = stot[tid] - c0;
    lofs[tid + 256] = stot[tid + 256] - c1;
    __syncthreads();
    // place into bucket-sorted LDS arrays
#pragma unroll
    for (int i = 0; i < 16; ++i) {
      int bucket = rb[i] >> 12;
      int r = rb[i] & 4095;
      int lp = lofs[bucket] + r;
      sortedv[lp] = vals[i];
      sorteda[lp] = sofs[bucket] + r;
    }
    __syncthreads();
    // coalesced-ish stream-out
#pragma unroll
    for (int i = 0; i < 16; ++i) {
      int idx = tid + 256 * i;
      ebuf[sorteda[idx]] = sortedv[idx];
    }
  } else {
    int wv = tid >> 6, lane = tid & 63;
    int nodebase = N + ((b - NSLICE) * 4 + wv) * 32;  // nodes [N, 2N)
    xw_tile(nodebase, lane, x1, x2, W, y);
  }
}

// P6: per-bucket CSR finalize (contiguous edge segment). LDS count+scan+scatter.
__global__ __launch_bounds__(256) void k_p6(const int* __restrict__ ebuf, const int* __restrict__ tot,
                                            int* __restrict__ rowptr, int* __restrict__ col) {
  __shared__ int stot[NBUCKET];
  __shared__ int c256[256];
  __shared__ int lofs[256];
  int b = blockIdx.x, t = threadIdx.x;
  {
    int v0 = tot[t], v1 = tot[t + 256];
    stot[t] = v0;
    stot[t + 256] = v1;
    __syncthreads();
    for (int d = 1; d < NBUCKET; d <<= 1) {
      int a0 = (t >= d) ? stot[t - d] : 0;
      int a1 = (t + 256 >= d) ? stot[t + 256 - d] : 0;
      __syncthreads();
      stot[t] += a0;
      stot[t + 256] += a1;
      __syncthreads();
    }
  }
  int e0 = (b == 0) ? 0 : stot[b - 1];
  int e1 = stot[b];
  c256[t] = 0;
  __syncthreads();
  for (int i = e0 + t; i < e1; i += 256) atomicAdd(&c256[(ebuf[i] >> 17) & 255], 1);
  __syncthreads();
  int v = c256[t];
  lofs[t] = v;
  __syncthreads();
  for (int d = 1; d < 256; d <<= 1) {
    int a = (t >= d) ? lofs[t - d] : 0;
    __syncthreads();
    lofs[t] += a;
    __syncthreads();
  }
  int excl = lofs[t] - v;
  rowptr[b * 256 + t] = e0 + excl;
  if (b == 0 && t == 0) rowptr[N2] = 2 * E;
  c256[t] = 0;
  lofs[t] = excl;
  __syncthreads();
  for (int i = e0 + t; i < e1; i += 256) {
    int pk = ebuf[i];
    int dl = (pk >> 17) & 255;
    int r = atomicAdd(&c256[dl], 1);
    col[e0 + lofs[dl] + r] = pk & 0x1FFFF;
  }
}

// ---------------- gather: out[n] = relu(in[n] + sum_{j->n} in[j] + bias), fp16 rows ----------------
// TWO nodes per wave (32-lane groups, __half2 loads). ONE clamped 32-wide col load with
// PRE-SCALED element offsets (saves a shift per edge); lanes >= deg already hold col[last]
// -> constant shfl index, fully unconditional 16-deep load bursts. DEPTH-2 fp16 pre-reduce
// tree (3 hadd2 per 4 slots) then f32 accumulate; duplicates removed by one subtract.

__global__ __launch_bounds__(256) void k_gather(const __half* __restrict__ in, const int* __restrict__ rowptr,
                                                const int* __restrict__ col, const float* __restrict__ bias,
                                                __half* __restrict__ outb) {
  int tid = threadIdx.x;
  int lane32 = tid & 31;
  int n = blockIdx.x * 8 + (tid >> 5);
  const __half2* in2 = (const __half2*)in;     // row = 32 half2
  __half2* out2 = (__half2*)outb;
  float2 bias2 = ((const float2*)bias)[lane32];
  int p0 = rowptr[n], p1 = rowptr[n + 1];
  int deg = p1 - p0;
  int pc = (p1 - 1 > p0) ? p1 - 1 : p0;        // clamp target (deg==0 safe)
  int cidx = p0 + lane32;
  int c0s = col[cidx < pc ? cidx : pc] * 32;   // pre-scaled half2-element offset
  __half2 self = in2[(size_t)n * 32 + lane32];
  float ax = __half2float(self.x) + bias2.x;
  float ay = __half2float(self.y) + bias2.y;
  float cx = 0.f, cy = 0.f;
  if (deg > 0) {
    __half2 vl;
    {  // batch 0: edges 0..15
      __half2 v[16];
#pragma unroll
      for (int i = 0; i < 16; ++i) {
        int co = __shfl(c0s, i, 32);
        v[i] = in2[(size_t)(unsigned)(co + lane32)];
      }
#pragma unroll
      for (int i = 0; i < 16; i += 4) {
        __half2 u = __hadd2(__hadd2(v[i], v[i + 1]), __hadd2(v[i + 2], v[i + 3]));
        if ((i & 4) == 0) {
          ax += __half2float(u.x);
          ay += __half2float(u.y);
        } else {
          cx += __half2float(u.x);
          cy += __half2float(u.y);
        }
      }
      vl = v[15];
    }
    if (deg > 16) {  // batch 1: edges 16..31
      __half2 v[16];
#pragma unroll
      for (int i = 0; i < 16; ++i) {
        int co = __shfl(c0s, i + 16, 32);
        v[i] = in2[(size_t)(unsigned)(co + lane32)];
      }
#pragma unroll
      for (int i = 0; i < 16; i += 4) {
        __half2 u = __hadd2(__hadd2(v[i], v[i + 1]), __hadd2(v[i + 2], v[i + 3]));
        if ((i & 4) == 0) {
          ax += __half2float(u.x);
          ay += __half2float(u.y);
        } else {
          cx += __half2float(u.x);
          cy += __half2float(u.y);
        }
      }
      vl = v[15];
    }
    if (deg > 32) {  // ultra-rare overflow (P ~ 2e-4 per node-half)
      for (int p = p0 + 32; p < p1; ++p) {
        int c = col[p];
        __half2 v = in2[(size_t)c * 32 + lane32];
        ax += __half2float(v.x);
        ay += __half2float(v.y);
      }
    }
    // correction: all duplicate slots hold the SAME row (col[pc]); vl holds it whenever dup>0
    int cov = (deg > 16) ? 32 : 16;
    int dup = cov - (deg < cov ? deg : cov);
    float fd = (float)dup;
    ax -= fd * __half2float(vl.x);
    ay -= fd * __half2float(vl.y);
  }
  __half2 o;
  o.x = __float2half(fmaxf(ax + cx, 0.f));
  o.y = __float2half(fmaxf(ay + cy, 0.f));
  out2[(size_t)n * 32 + lane32] = o;
}

// ---------------- k_mid via MFMA: z = relu(in@Wa + ba) @ Wb, all in registers ----------------
__global__ __launch_bounds__(256) void k_mid(const __half* __restrict__ in, const __half* __restrict__ WaT,
                                             const float* __restrict__ ba, const __half* __restrict__ WbT,
                                             __half* __restrict__ outb) {
  int tid = threadIdx.x, wv = tid >> 6, lane = tid & 63;
  int nodebase = (blockIdx.x * 4 + wv) * 32;
  int r = lane & 31, kh = lane >> 5;
  // ---- matmul 1 (swapped): acc0 = h1 rows 0..31, acc1 = h1 rows 32..63; cols = nodes
  f32x16 acc0, acc1;
#pragma unroll
  for (int i = 0; i < 16; ++i) { acc0[i] = 0.f; acc1[i] = 0.f; }
  const __half* brow = in + (size_t)(nodebase + r) * H + kh * 8;
#pragma unroll
  for (int kk = 0; kk < 4; ++kk) {
    f16x8 bf = ldf16x8(brow + kk * 16);
    f16x8 a0 = ldf16x8(WaT + (size_t)r * H + kk * 16 + kh * 8);
    f16x8 a1 = ldf16x8(WaT + (size_t)(r + 32) * H + kk * 16 + kh * 8);
    acc0 = __builtin_amdgcn_mfma_f32_32x32x16_f16(a0, bf, acc0, 0, 0, 0);
    acc1 = __builtin_amdgcn_mfma_f32_32x32x16_f16(a1, bf, acc1, 0, 0, 0);
  }
  // ---- bias + relu + pack to half pairs (rows = h1)
  float bav = ba[lane];  // lanes 0..63 cover h1 0..63
  unsigned p0[8], p1[8];
#pragma unroll
  for (int g2 = 0; g2 < 8; ++g2) {
    int regA = 2 * g2, regB = 2 * g2 + 1;
    int rowA = (regA & 3) + 8 * (regA >> 2) + 4 * kh;
    int rowB = (regB & 3) + 8 * (regB >> 2) + 4 * kh;
    float tA0 = fmaxf(acc0[regA] + __shfl(bav, rowA, 64), 0.f);
    float tB0 = fmaxf(acc0[regB] + __shfl(bav, rowB, 64), 0.f);
    float tA1 = fmaxf(acc1[regA] + __shfl(bav, rowA + 32, 64), 0.f);
    float tB1 = fmaxf(acc1[regB] + __shfl(bav, rowB + 32, 64), 0.f);
    p0[g2] = packh(tA0, tB0);
    p1[g2] = packh(tA1, tB1);
  }
  unsigned q0[8], q1[8];
#pragma unroll
  for (int i = 0; i < 8; ++i) {
    q0[i] = (unsigned)__shfl_xor((int)p0[i], 32, 64);
    q1[i] = (unsigned)__shfl_xor((int)p1[i], 32, 64);
  }
  // ---- matmul 2 (standard): out rows = nodes, cols = h2
  bool hi = (kh != 0);
  f32x16 o0, o1;
#pragma unroll
  for (int i = 0; i < 16; ++i) { o0[i] = 0.f; o1[i] = 0.f; }
#pragma unroll
  for (int kk = 0; kk < 4; ++kk) {
    const unsigned* P = (kk < 2) ? p0 : p1;
    const unsigned* Q = (kk < 2) ? q0 : q1;
    int s = kk & 1;
    FragU f;
    f.u[0] = hi ? Q[4 * s + 2] : P[4 * s + 0];
    f.u[1] = hi ? Q[4 * s + 3] : P[4 * s + 1];
    f.u[2] = hi ? P[4 * s + 2] : Q[4 * s + 0];
    f.u[3] = hi ? P[4 * s + 3] : Q[4 * s + 1];
    f16x8 b0 = ldf16x8(WbT + (size_t)r * H + kk * 16 + kh * 8);
    f16x8 b1 = ldf16x8(WbT + (size_t)(r + 32) * H + kk * 16 + kh * 8);
    o0 = __builtin_amdgcn_mfma_f32_32x32x16_f16(f.v, b0, o0, 0, 0, 0);
    o1 = __builtin_amdgcn_mfma_f32_32x32x16_f16(f.v, b1, o1, 0, 0, 0);
  }
#pragma unroll
  for (int reg = 0; reg < 16; ++reg) {
    int row = (reg & 3) + 8 * (reg >> 2) + 4 * kh;
    outb[(size_t)(nodebase + row) * H + r]      = __float2half(o0[reg]);
    outb[(size_t)(nodebase + row) * H + r + 32] = __float2half(o1[reg]);
  }
}

// ---------------- k_last via MFMA: h = relu(in@Wc + b4); normalize rows; pool partials ----
__global__ __launch_bounds__(256) void k_last(const __half* __restrict__ in, const __half* __restrict__ WcT,
                                              const float* __restrict__ b4, __half* __restrict__ outn,
                                              float* __restrict__ pg) {
  int tid = threadIdx.x, wv = tid >> 6, lane = tid & 63;
  int tile = blockIdx.x * 4 + wv;
  int nodebase = tile * 32;
  int r = lane & 31, kh = lane >> 5;
  f32x16 acc0, acc1;
#pragma unroll
  for (int i = 0; i < 16; ++i) { acc0[i] = 0.f; acc1[i] = 0.f; }
  const __half* arow = in + (size_t)(nodebase + r) * H + kh * 8;
#pragma unroll
  for (int kk = 0; kk < 4; ++kk) {
    f16x8 af = ldf16x8(arow + kk * 16);
    f16x8 b0 = ldf16x8(WcT + (size_t)r * H + kk * 16 + kh * 8);
    f16x8 b1 = ldf16x8(WcT + (size_t)(r + 32) * H + kk * 16 + kh * 8);
    acc0 = __builtin_amdgcn_mfma_f32_32x32x16_f16(af, b0, acc0, 0, 0, 0);
    acc1 = __builtin_amdgcn_mfma_f32_32x32x16_f16(af, b1, acc1, 0, 0, 0);
  }
  float bA = b4[r], bB = b4[r + 32];
  float psum0 = 0.f, psum1 = 0.f;
#pragma unroll
  for (int reg = 0; reg < 16; ++reg) {
    int row = (reg & 3) + 8 * (reg >> 2) + 4 * kh;
    float h0 = fmaxf(acc0[reg] + bA, 0.f);
    float h1 = fmaxf(acc1[reg] + bB, 0.f);
    psum0 += h0;
    psum1 += h1;
    float ss = h0 * h0 + h1 * h1;
#pragma unroll
    for (int d = 1; d < 32; d <<= 1) ss += __shfl_xor(ss, d, 64);
    float inv = 1.f / fmaxf(sqrtf(ss), 1e-12f);
    outn[(size_t)(nodebase + row) * H + r]      = __float2half(h0 * inv);
    outn[(size_t)(nodebase + row) * H + r + 32] = __float2half(h1 * inv);
  }
  psum0 += __shfl_xor(psum0, 32, 64);
  psum1 += __shfl_xor(psum1, 32, 64);
  if (kh == 0) {
    pg[tile * 64 + r]      = psum0;
    pg[tile * 64 + r + 32] = psum1;
  }
}

// ---------------- fused sim + hist + stats via MFMA (fp16 inputs, f32 accum) ----------------
__global__ __launch_bounds__(256) void k_sim(const __half* __restrict__ Hn, float* __restrict__ psum,
                                             float* __restrict__ psumsq, float* __restrict__ pmax,
                                             int* __restrict__ phist) {
  __shared__ int shist[64 * 17];   // 64 replicas, stride 17
  __shared__ float sfin[4][4];
  int tid = threadIdx.x, lane = tid & 63, wv = tid >> 6;
  int g = blockIdx.x >> 3, rt = blockIdx.x & 7;
  for (int i = tid; i < 64 * 17; i += 256) shist[i] = 0;
  __syncthreads();

  int rtile = wv & 1;   // 32-row subtile within the 64-row block tile
  int cgrp  = wv >> 1;  // col-tile group: 8 tiles of 32 cols each
  int arow = lane & 31;
  int koff = (lane >> 5) * 8;  // K-half select (identical formula for A and B)

  const __half* H1 = Hn + ((size_t)g * NPG + rt * 64 + rtile * 32 + arow) * H + koff;
  f16x8 afrag[4];
#pragma unroll
  for (int kk = 0; kk < 4; ++kk) afrag[kk] = ldf16x8(H1 + kk * 16);

  const __half* H2g = Hn + ((size_t)N + (size_t)g * NPG + arow) * H + koff;
  float lmax = -2.f, lsum = 0.f, lsumsq = 0.f;
  int rep = lane * 17;
#pragma unroll 1
  for (int t = 0; t < 8; ++t) {
    int ct = cgrp * 8 + t;
    const __half* B0 = H2g + (size_t)(ct * 32) * H;
    f32x16 acc;
#pragma unroll
    for (int r = 0; r < 16; ++r) acc[r] = 0.f;
#pragma unroll
    for (int kk = 0; kk < 4; ++kk) {
      f16x8 bfrag = ldf16x8(B0 + kk * 16);
      acc = __builtin_amdgcn_mfma_f32_32x32x16_f16(afrag[kk], bfrag, acc, 0, 0, 0);
    }
#pragma unroll
    for (int r = 0; r < 16; ++r) {
      float v = acc[r];
      lmax = fmaxf(lmax, v);
      lsum += v;
      lsumsq = fmaf(v, v, lsumsq);
      int bin = (int)((v + 1.f) * 8.f);  // trunc==floor for v>=-1; clamp handles rest
      bin = bin < 0 ? 0 : (bin > BINS - 1 ? BINS - 1 : bin);
      atomicAdd(&shist[rep + bin], 1);
    }
  }
#pragma unroll
  for (int d = 1; d < 64; d <<= 1) {
    lsum += __shfl_xor(lsum, d, 64);
    lsumsq += __shfl_xor(lsumsq, d, 64);
    lmax = fmaxf(lmax, __shfl_xor(lmax, d, 64));
  }
  if (lane == 0) {
    sfin[wv][0] = lsum;
    sfin[wv][1] = lsumsq;
    sfin[wv][2] = lmax;
  }
  __syncthreads();
  if (tid == 0) {
    psum[blockIdx.x] = sfin[0][0] + sfin[1][0] + sfin[2][0] + sfin[3][0];
    psumsq[blockIdx.x] = sfin[0][1] + sfin[1][1] + sfin[2][1] + sfin[3][1];
    pmax[blockIdx.x] = fmaxf(fmaxf(sfin[0][2], sfin[1][2]), fmaxf(sfin[2][2], sfin[3][2]));
  }
  if (tid < BINS) {
    int tot = 0;
    for (int r = 0; r < 64; ++r) tot += shist[r * 17 + tid];
    phist[blockIdx.x * BINS + tid] = tot;
  }
}

// ---------------- final feature assembly + MLP ----------------
__global__ __launch_bounds__(64) void k_final(const float* __restrict__ pg1, const float* __restrict__ pg2,
                                              const float* __restrict__ psum, const float* __restrict__ psumsq,
                                              const float* __restrict__ pmax, const int* __restrict__ phist,
                                              const float* __restrict__ w1, const float* __restrict__ b1,
                                              const float* __restrict__ w2, const float* __restrict__ b2,
                                              const float* __restrict__ w3, const float* __restrict__ b3,
                                              float* __restrict__ out) {
  __shared__ float f[FIN + 1];
  __shared__ float t1[64];
  __shared__ float t2[32];
  int g = blockIdx.x, t = threadIdx.x;
  {
    float s1v = 0.f, s2v = 0.f;
#pragma unroll
    for (int r = 0; r < 16; ++r) {
      s1v += pg1[(g * 16 + r) * 64 + t];
      s2v += pg2[(g * 16 + r) * 64 + t];
    }
    f[t]      = s1v * (1.f / NPG);
    f[64 + t] = s2v * (1.f / NPG);
  }
  if (t < BINS) {
    int tot = 0;
#pragma unroll
    for (int r = 0; r < 8; ++r) tot += phist[(g * 8 + r) * BINS + t];
    f[2 * H + t] = (float)tot * (1.f / 262144.f);
  }
  if (t == 0) {
    float s = 0.f, ss = 0.f, mx = -2.f;
#pragma unroll
    for (int r = 0; r < 8; ++r) {
      s += psum[g * 8 + r];
      ss += psumsq[g * 8 + r];
      mx = fmaxf(mx, pmax[g * 8 + r]);
    }
    const float inv = 1.f / 262144.f;
    float mean = s * inv;
    float var = fmaxf(ss * inv - mean * mean, 0.f);
    f[144] = mean;
    f[145] = mx;
    f[146] = sqrtf(var);
  }
  __syncthreads();
  float acc = b1[t];
  for (int k = 0; k < FIN; ++k) acc = fmaf(f[k], w1[k * 64 + t], acc);
  t1[t] = fmaxf(acc, 0.f);
  __syncthreads();
  if (t < 32) {
    float a2 = b2[t];
#pragma unroll 8
    for (int k = 0; k < 64; ++k) a2 = fmaf(t1[k], w2[k * 32 + t], a2);
    t2[t] = fmaxf(a2, 0.f);
  }
  __syncthreads();
  if (t == 0) {
    float a3 = b3[0];
#pragma unroll
    for (int k = 0; k < 32; ++k) a3 = fmaf(t2[k], w3[k], a3);
    out[g] = a3;
  }
}

}  // namespace

extern "C" void kernel_launch(void* const* d_in, const int* in_sizes, int n_in, void* d_out, int out_size,
                              void* d_ws, size_t ws_size, hipStream_t stream) {
  const float* x1 = (const float*)d_in[0];
  const int* e1 = (const int*)d_in[1];
  const float* x2 = (const float*)d_in[3];
  const int* e2 = (const int*)d_in[4];
  const float* enc_w1 = (const float*)d_in[6];
  const float* enc_b1 = (const float*)d_in[7];
  const float* enc_w2 = (const float*)d_in[8];
  const float* enc_b2 = (const float*)d_in[9];
  const float* enc_w3 = (const float*)d_in[10];
  const float* enc_b3 = (const float*)d_in[11];
  const float* enc_w4 = (const float*)d_in[12];
  const float* enc_b4 = (const float*)d_in[13];
  const float* mw1 = (const float*)d_in[14];
  const float* mb1 = (const float*)d_in[15];
  const float* mw2 = (const float*)d_in[16];
  const float* mb2 = (const float*)d_in[17];
  const float* mw3 = (const float*)d_in[18];
  const float* mb3 = (const float*)d_in[19];
  float* out = (float*)d_out;

  char* wsc = (char*)d_ws;
  size_t off = 0;
  auto alloc = [&](size_t bytes) -> void* {
    void* p = wsc + off;
    off += (bytes + 255) & ~(size_t)255;
    return p;
  };
  __half* Hn = (__half*)alloc((size_t)N2 * H * 2);        // 16 MB (normalized embeddings, fp16)
  __half* yH = (__half*)alloc((size_t)N2 * H * 2);        // 16 MB
  __half* tH = (__half*)alloc((size_t)N2 * H * 2);        // 16 MB (aliased as ebuf during CSR build)
  __half* zH = (__half*)alloc((size_t)N2 * H * 2);        // 16 MB
  __half* t2H = (__half*)alloc((size_t)N2 * H * 2);       // 16 MB
  int* rowptr = (int*)alloc((size_t)(N2 + 1) * 4);
  int* colidx = (int*)alloc((size_t)2 * E * 4);           // 8 MB
  int* bcnt = (int*)alloc((size_t)NSLICE * NBUCKET * 4);  // 1 MB
  int* boffs = (int*)alloc((size_t)NBUCKET * NSLICE * 4); // 1 MB
  int* tot = (int*)alloc((size_t)NBUCKET * 4);
  float* pg = (float*)alloc((size_t)(N2 / 32) * 64 * 4);  // 1 MB
  float* psum = (float*)alloc(1024 * 4);
  float* psumsq = (float*)alloc(1024 * 4);
  float* pmaxa = (float*)alloc(1024 * 4);
  int* phist = (int*)alloc((size_t)1024 * BINS * 4);
  __half* WaT = (__half*)alloc(4096 * 2);
  __half* WbT = (__half*)alloc(4096 * 2);
  __half* WcT = (__half*)alloc(4096 * 2);
  (void)ws_size;
  (void)in_sizes;
  (void)n_in;
  (void)out_size;

  const int* src1 = e1;
  const int* dst1 = e1 + E;
  const int* src2 = e2;
  const int* dst2 = e2 + E;
  int* ebuf = (int*)tH;  // 8 MB; consumed by k_p6 before k_gather writes tH

  // CSR build with xw MFMA overlapped; LDS bucket-sorted scatter for coalesced ebuf writes
  k_hist<<<NSLICE + 16, 256, 0, stream>>>(dst1, dst2, bcnt, enc_w2, enc_w3, enc_w4, WaT, WbT, WcT);
  k_scan_xw<<<NBUCKET + 512, 256, 0, stream>>>(bcnt, boffs, tot, x1, x2, enc_w1, yH);
  k_p5_xw<<<NSLICE + 512, 256, 0, stream>>>(src1, dst1, src2, dst2, boffs, tot, ebuf, x1, x2, enc_w1, yH);
  k_p6<<<NBUCKET, 256, 0, stream>>>(ebuf, tot, rowptr, colidx);

  // encoder over 2N nodes (split kernels: gather = 2 nodes/wave, depth-2 pk_add tree)
  k_gather<<<N2 / 8, 256, 0, stream>>>(yH, rowptr, colidx, enc_b1, tH);
  k_mid<<<N2 / 128, 256, 0, stream>>>(tH, WaT, enc_b2, WbT, zH);
  k_gather<<<N2 / 8, 256, 0, stream>>>(zH, rowptr, colidx, enc_b3, t2H);
  k_last<<<N2 / 128, 256, 0, stream>>>(t2H, WcT, enc_b4, Hn, pg);

  k_sim<<<B * 8, 256, 0, stream>>>(Hn, psum, psumsq, pmaxa, phist);
  k_final<<<B, 64, 0, stream>>>(pg, pg + (size_t)2048 * 64, psum, psumsq, pmaxa, phist, mw1, mb1, mw2, mb2,
                                mw3, mb3, out);
}